// Round 3
// baseline (917.754 us; speedup 1.0000x reference)
//
#include <hip/hip_runtime.h>
#include <hip/hip_bf16.h>
#include <math.h>

// Problem constants (from reference)
#define NNODES 10000
#define MPAD   10112    // 79 * 128
#define EDGES  160000
#define EPLUS  170000   // EDGES + NNODES self-loops
#define FIN    512
#define HEADS8 8
#define CH     64
#define HC     512      // HEADS8*CH
#define NG     64       // graphs
#define NCLS   64
#define NCOPY  16       // shadow copies for bn atomic accumulators
#define AGG_BLKS 2500   // NNODES/4: 4 waves per block, 1 node per wave

typedef _Float16 f16x8 __attribute__((ext_vector_type(8)));
typedef _Float16 f16x4 __attribute__((ext_vector_type(4)));
typedef _Float16 f16x2 __attribute__((ext_vector_type(2)));
typedef float    f32x4 __attribute__((ext_vector_type(4)));

#define GLD_LDS16(g, l)                                                        \
    __builtin_amdgcn_global_load_lds(                                          \
        (const __attribute__((address_space(1))) void*)(g),                    \
        (__attribute__((address_space(3))) void*)(l), 16, 0, 0)

// bnacc layout (floats):
//  L1 sum @0       [NCOPY*512]   L1 sq @8192   [NCOPY*512]
//  L2 sum @16384   [NCOPY*512]   L2 sq @24576  [NCOPY*512]
//  L3 sum @32768   [NCOPY*64]    L3 sq @33792  [NCOPY*64]
#define BNACC_N 34816

// ---------------------------------------------------------------------------
// Fused prep: [0,665) dst-degree histogram + graph offsets (+ bnacc zeroing);
//             [665,5665) fp32->fp16 convert of x_in;
//             [5665,...) 4 weight transposes (fp32 KxN -> fp16 NxK)
// ---------------------------------------------------------------------------
#define PREP_CNT  665
#define PREP_CONV 5000   // 10000*512/4 / 256
__global__ void prep_all(const int* __restrict__ ei, int* __restrict__ deg,
                         const int* __restrict__ batch, int* __restrict__ goff,
                         const float* __restrict__ x_in, _Float16* __restrict__ x16,
                         const float* __restrict__ Wa, const float* __restrict__ Wb,
                         const float* __restrict__ Wc, const float* __restrict__ Wd,
                         _Float16* __restrict__ Ta, _Float16* __restrict__ Tb,
                         _Float16* __restrict__ Tc, _Float16* __restrict__ Td,
                         int* __restrict__ tickets, float* __restrict__ bnacc)
{
    const int b   = blockIdx.x;
    const int tid = threadIdx.x;
    if (b < PREP_CNT) {
        if (b == 0 && tid < 4) tickets[tid] = 0;
        if (b < 8) {   // zero bn accumulators: 34816 floats = 8704 float4
            float4 z4 = make_float4(0.f, 0.f, 0.f, 0.f);
            float4* bz = (float4*)bnacc;
            for (int i = tid; i < 1088; i += 256)
                bz[b * 1088 + i] = z4;
        }
        int e = b * 256 + tid;
        if (e < NNODES) {
            int bb = batch[e];
            int bprev = (e == 0) ? -1 : batch[e - 1];
            for (int g = bprev + 1; g <= bb; ++g) goff[g] = e;
            if (e == NNODES - 1)
                for (int g = bb + 1; g <= NG; ++g) goff[g] = NNODES;
        }
        if (e >= EPLUS) return;
        int dst = (e < EDGES) ? ei[EDGES + e] : (e - EDGES);
        atomicAdd(&deg[dst], 1);
    } else if (b < PREP_CNT + PREP_CONV) {
        int i = (b - PREP_CNT) * 256 + tid;
        float4 v = ((const float4*)x_in)[i];
        f16x4 o;
        o[0] = (_Float16)v.x; o[1] = (_Float16)v.y;
        o[2] = (_Float16)v.z; o[3] = (_Float16)v.w;
        ((f16x4*)x16)[i] = o;
    } else {
        int tb = b - (PREP_CNT + PREP_CONV);
        int z  = tb >> 8;            // 0..3
        int rem = tb & 255;
        int bxi = rem & 15, byi = rem >> 4;
        if (z == 3 && bxi >= 2) return;   // W3 has only 64 cols
        const float* W = (z == 0) ? Wa : (z == 1) ? Wb : (z == 2) ? Wc : Wd;
        _Float16*    T = (z == 0) ? Ta : (z == 1) ? Tb : (z == 2) ? Tc : Td;
        const int ldW = (z == 3) ? 64 : 512;
        __shared__ float t[32][33];
        int bx = bxi * 32, by = byi * 32;
        int tx = tid & 31, ty = tid >> 5;   // 32 x 8
        #pragma unroll
        for (int i = 0; i < 32; i += 8)
            t[ty + i][tx] = W[(size_t)(by + ty + i) * ldW + bx + tx];
        __syncthreads();
        #pragma unroll
        for (int i = 0; i < 32; i += 8)
            T[(size_t)(bx + ty + i) * 512 + by + tx] = (_Float16)t[tx][ty + i];
    }
}

// ---------------------------------------------------------------------------
// Device-side exclusive scan of deg (tail block of the encoder GEMM launch)
// ---------------------------------------------------------------------------
__device__ void exscan_dev(const int* __restrict__ deg, int* __restrict__ off,
                           int* __restrict__ cursor, int* partial /* LDS[256] */)
{
    const int tid = threadIdx.x;
    const int chunk = (NNODES + 255) / 256; // 40
    int begin = tid * chunk;
    int end   = begin + chunk; if (end > NNODES) end = NNODES;
    if (begin > NNODES) begin = NNODES;
    int s = 0;
    for (int i = begin; i < end; ++i) s += deg[i];
    partial[tid] = s;
    __syncthreads();
    for (int o = 1; o < 256; o <<= 1) {
        int v = (tid >= o) ? partial[tid - o] : 0;
        __syncthreads();
        partial[tid] += v;
        __syncthreads();
    }
    int run = (tid > 0) ? partial[tid - 1] : 0;  // exclusive prefix
    for (int i = begin; i < end; ++i) {
        off[i] = run; cursor[i] = run; run += deg[i];
    }
    if (tid == 255) off[NNODES] = run; // == EPLUS
}

// ---------------------------------------------------------------------------
// fp16 MFMA GEMM: C[M,N] = A16[M,K] @ Bt16[N,K]^T (+bias), 128x64 tile.
// Optional fused per-head attention scores (64-col tile == one head).
// tail==1: exscan (1 extra block); tail==2: CSR scatter (665 extra blocks).
// ---------------------------------------------------------------------------
__global__ __launch_bounds__(256) void gemm_f16_mfma(
    const _Float16* __restrict__ A16, const _Float16* __restrict__ Bt16,
    const float* __restrict__ bias, _Float16* __restrict__ C16,
    float* __restrict__ ssrc, float* __restrict__ sdst,
    const float* __restrict__ a_s, const float* __restrict__ a_d,
    int Mt, int Nn, int K,
    int tail, const int* __restrict__ tp0, int* __restrict__ tp1,
    int* __restrict__ tp2)
{
    __shared__ _Float16 As[128 * 32] __attribute__((aligned(16)));
    __shared__ _Float16 Bs[64 * 32]  __attribute__((aligned(16)));
    __shared__ float sS[2][128];
    __shared__ float sD[2][128];
    const int tid  = threadIdx.x;
    const int ncols = Nn >> 6;
    const int nb    = ncols * (Mt >> 7);
    const int bid   = blockIdx.x;

    if (bid >= nb) {   // tail work, overlapped with the GEMM blocks
        if (tail == 1) {
            exscan_dev(tp0, tp1, tp2, (int*)As);
        } else if (tail == 2) {
            int e = (bid - nb) * 256 + tid;
            if (e < EPLUS) {
                int srcN, dstN;
                if (e < EDGES) { srcN = tp0[e]; dstN = tp0[EDGES + e]; }
                else           { srcN = dstN = e - EDGES; }
                int pos = atomicAdd(&tp1[dstN], 1);
                tp2[pos] = srcN;
            }
        }
        return;
    }

    const int bt   = bid % ncols;        // col tile (== head when Nn==512)
    const int row0 = (bid / ncols) * 128;
    const int col0 = bt * 64;
    const int wave = tid >> 6;
    const int lane = tid & 63;
    const int wy = wave >> 1, wx = wave & 1;

    const int lrow = lane >> 2;
    const int lk   = (lane & 3) * 8;

    f32x4 acc[4][2] = {};

    for (int k0 = 0; k0 < K; k0 += 32) {
        if (k0) __syncthreads();
        #pragma unroll
        for (int r = 0; r < 2; ++r) {
            const int chunk = r * 4 + wave;
            const int trow  = chunk * 16 + lrow;
            GLD_LDS16(A16 + (size_t)(row0 + trow) * K + k0 + lk,
                      &As[chunk * 512]);
        }
        {
            const int trow = wave * 16 + lrow;
            GLD_LDS16(Bt16 + (size_t)(col0 + trow) * K + k0 + lk,
                      &Bs[wave * 512]);
        }
        __syncthreads();

        const int quad = lane >> 4;
        const int l16  = lane & 15;
        f16x8 af[4], bf[2];
        #pragma unroll
        for (int m = 0; m < 4; ++m)
            af[m] = *(const f16x8*)&As[(wy * 64 + m * 16 + l16) * 32 + quad * 8];
        #pragma unroll
        for (int n = 0; n < 2; ++n)
            bf[n] = *(const f16x8*)&Bs[(wx * 32 + n * 16 + l16) * 32 + quad * 8];
        #pragma unroll
        for (int m = 0; m < 4; ++m)
            #pragma unroll
            for (int n = 0; n < 2; ++n)
                acc[m][n] = __builtin_amdgcn_mfma_f32_16x16x32_f16(
                    af[m], bf[n], acc[m][n], 0, 0, 0);
    }

    const int quad = lane >> 4;
    const int l16  = lane & 15;
    #pragma unroll
    for (int m = 0; m < 4; ++m) {
        #pragma unroll
        for (int n = 0; n < 2; ++n) {
            const int col = col0 + wx * 32 + n * 16 + l16;
            const float bv = bias ? bias[col] : 0.0f;
            #pragma unroll
            for (int r = 0; r < 4; ++r) {
                const int row = row0 + wy * 64 + m * 16 + quad * 4 + r;
                C16[(size_t)row * Nn + col] = (_Float16)(acc[m][n][r] + bv);
            }
        }
    }

    if (ssrc) {   // fused per-head scores (bias-less layer GEMMs)
        float a_sv[2], a_dv[2];
        #pragma unroll
        for (int n = 0; n < 2; ++n) {
            const int col = col0 + wx * 32 + n * 16 + l16;
            a_sv[n] = a_s[col & 511];
            a_dv[n] = a_d[col & 511];
        }
        #pragma unroll
        for (int m = 0; m < 4; ++m) {
            #pragma unroll
            for (int r = 0; r < 4; ++r) {
                float vs = acc[m][0][r] * a_sv[0] + acc[m][1][r] * a_sv[1];
                float vd = acc[m][0][r] * a_dv[0] + acc[m][1][r] * a_dv[1];
                vs += __shfl_xor(vs, 1); vs += __shfl_xor(vs, 2);
                vs += __shfl_xor(vs, 4); vs += __shfl_xor(vs, 8);
                vd += __shfl_xor(vd, 1); vd += __shfl_xor(vd, 2);
                vd += __shfl_xor(vd, 4); vd += __shfl_xor(vd, 8);
                if (l16 == 0) {
                    const int lr = wy * 64 + m * 16 + quad * 4 + r;
                    sS[wx][lr] = vs;
                    sD[wx][lr] = vd;
                }
            }
        }
        __syncthreads();
        if (wx == 0 && l16 == 0) {
            const int head = bt;   // Nn==512: col tile == head
            #pragma unroll
            for (int m = 0; m < 4; ++m)
                #pragma unroll
                for (int r = 0; r < 4; ++r) {
                    const int lr = wy * 64 + m * 16 + quad * 4 + r;
                    const int row = row0 + lr;
                    ssrc[(size_t)row * HEADS8 + head] = sS[0][lr] + sS[1][lr];
                    sdst[(size_t)row * HEADS8 + head] = sD[0][lr] + sD[1][lr];
                }
        }
    }
}

// ---------------------------------------------------------------------------
// fp16 MFMA GEMM, N=64 (layer 3) with fused NH=1 scores. Padded rows.
// ---------------------------------------------------------------------------
__global__ __launch_bounds__(256) void gemm_f16_mfma_n64(
    const _Float16* __restrict__ A16, const _Float16* __restrict__ Bt16,
    _Float16* __restrict__ C16,
    float* __restrict__ ssrc, float* __restrict__ sdst,
    const float* __restrict__ a_s, const float* __restrict__ a_d)
{
    __shared__ _Float16 As[64 * 32] __attribute__((aligned(16)));
    __shared__ _Float16 Bs[64 * 32] __attribute__((aligned(16)));
    __shared__ float sS[2][64];
    __shared__ float sD[2][64];
    const int tid  = threadIdx.x;
    const int wave = tid >> 6;
    const int lane = tid & 63;
    const int row0 = blockIdx.x * 64;
    const int wy = wave >> 1, wx = wave & 1;

    const int lrow = lane >> 2;
    const int lk   = (lane & 3) * 8;

    f32x4 acc[2][2] = {};

    for (int k0 = 0; k0 < 512; k0 += 32) {
        if (k0) __syncthreads();
        {
            const int trow = wave * 16 + lrow;
            GLD_LDS16(A16 + (size_t)(row0 + trow) * 512 + k0 + lk, &As[wave * 512]);
            GLD_LDS16(Bt16 + (size_t)trow * 512 + k0 + lk, &Bs[wave * 512]);
        }
        __syncthreads();

        const int quad = lane >> 4;
        const int l16  = lane & 15;
        f16x8 af[2], bf[2];
        #pragma unroll
        for (int m = 0; m < 2; ++m)
            af[m] = *(const f16x8*)&As[(wy * 32 + m * 16 + l16) * 32 + quad * 8];
        #pragma unroll
        for (int n = 0; n < 2; ++n)
            bf[n] = *(const f16x8*)&Bs[(wx * 32 + n * 16 + l16) * 32 + quad * 8];
        #pragma unroll
        for (int m = 0; m < 2; ++m)
            #pragma unroll
            for (int n = 0; n < 2; ++n)
                acc[m][n] = __builtin_amdgcn_mfma_f32_16x16x32_f16(
                    af[m], bf[n], acc[m][n], 0, 0, 0);
    }

    const int quad = lane >> 4;
    const int l16  = lane & 15;
    #pragma unroll
    for (int m = 0; m < 2; ++m)
        #pragma unroll
        for (int n = 0; n < 2; ++n) {
            const int col = wx * 32 + n * 16 + l16;
            #pragma unroll
            for (int r = 0; r < 4; ++r) {
                const int row = row0 + wy * 32 + m * 16 + quad * 4 + r;
                C16[(size_t)row * 64 + col] = (_Float16)acc[m][n][r];
            }
        }

    // fused scores (heads=1)
    {
        float a_sv[2], a_dv[2];
        #pragma unroll
        for (int n = 0; n < 2; ++n) {
            const int col = wx * 32 + n * 16 + l16;
            a_sv[n] = a_s[col];
            a_dv[n] = a_d[col];
        }
        #pragma unroll
        for (int m = 0; m < 2; ++m)
            #pragma unroll
            for (int r = 0; r < 4; ++r) {
                float vs = acc[m][0][r] * a_sv[0] + acc[m][1][r] * a_sv[1];
                float vd = acc[m][0][r] * a_dv[0] + acc[m][1][r] * a_dv[1];
                vs += __shfl_xor(vs, 1); vs += __shfl_xor(vs, 2);
                vs += __shfl_xor(vs, 4); vs += __shfl_xor(vs, 8);
                vd += __shfl_xor(vd, 1); vd += __shfl_xor(vd, 2);
                vd += __shfl_xor(vd, 4); vd += __shfl_xor(vd, 8);
                if (l16 == 0) {
                    const int lr = wy * 32 + m * 16 + quad * 4 + r;
                    sS[wx][lr] = vs;
                    sD[wx][lr] = vd;
                }
            }
        __syncthreads();
        if (wx == 0 && l16 == 0) {
            #pragma unroll
            for (int m = 0; m < 2; ++m)
                #pragma unroll
                for (int r = 0; r < 4; ++r) {
                    const int lr = wy * 32 + m * 16 + quad * 4 + r;
                    const int row = row0 + lr;
                    ssrc[row] = sS[0][lr] + sS[1][lr];
                    sdst[row] = sD[0][lr] + sD[1][lr];
                }
        }
    }
}

// ---------------------------------------------------------------------------
// Segment-softmax aggregation NH=8 + FUSED BatchNorm stats.
// 2500 blocks x 256 threads; wave w owns node blockIdx*4+w (10000 node-waves,
// same gather parallelism as the 64-thread version). Per-wave LDS regions +
// wave_barrier (no __syncthreads inside the divergent edge loop). After the
// node loop: block LDS reduce -> 1 atomicAdd/channel/block into NCOPY shadow
// copies -> last-block ticket computes scale/shift in-kernel.
// ---------------------------------------------------------------------------
__global__ __launch_bounds__(256) void gat_aggregate8(
    const _Float16* __restrict__ Hf, const float* __restrict__ ssrc,
    const float* __restrict__ sdst, const int* __restrict__ off,
    const int* __restrict__ csr, const float* __restrict__ bias,
    _Float16* __restrict__ out,
    float* __restrict__ asum, float* __restrict__ asq,
    const float* __restrict__ g, const float* __restrict__ be,
    float* __restrict__ scale, float* __restrict__ shift,
    float invN, int* __restrict__ ticket)
{
    const int wv   = threadIdx.x >> 6;
    const int lane = threadIdx.x & 63;
    const int head = lane >> 3;
    const int n    = blockIdx.x * 4 + wv;    // always < NNODES (2500*4)

    __shared__ float exL[4][512];
    __shared__ int   srcL[4][64];
    float* exW  = exL[wv];
    int*   srcW = srcL[wv];

    const int e0 = off[n], e1 = off[n + 1];
    float4 sd0 = ((const float4*)(sdst + n * 8))[0];
    float4 sd1 = ((const float4*)(sdst + n * 8))[1];
    float sd[8] = {sd0.x, sd0.y, sd0.z, sd0.w, sd1.x, sd1.y, sd1.z, sd1.w};

    float acc[8]  = {};
    float ssum[8] = {};
    for (int base = e0; base < e1; base += 64) {
        int cnt = e1 - base; if (cnt > 64) cnt = 64;
        if (lane < cnt) {
            int s = csr[base + lane];
            srcW[lane] = s;
            float4 s0 = ((const float4*)(ssrc + s * 8))[0];
            float4 s1 = ((const float4*)(ssrc + s * 8))[1];
            float lv[8] = {s0.x, s0.y, s0.z, s0.w, s1.x, s1.y, s1.z, s1.w};
            #pragma unroll
            for (int h = 0; h < 8; ++h) {
                float l = lv[h] + sd[h];
                l = (l > 0.f) ? l : 0.2f * l;
                float ex = __expf(l);
                exW[lane * 8 + h] = ex;
                ssum[h] += ex;
            }
        }
        __builtin_amdgcn_wave_barrier();
        int j = 0;
        for (; j + 4 <= cnt; j += 4) {
            const int s0 = srcW[j],     s1 = srcW[j + 1];
            const int s2 = srcW[j + 2], s3 = srcW[j + 3];
            f16x8 h0 = *(const f16x8*)(Hf + (size_t)s0 * HC + lane * 8);
            f16x8 h1 = *(const f16x8*)(Hf + (size_t)s1 * HC + lane * 8);
            f16x8 h2 = *(const f16x8*)(Hf + (size_t)s2 * HC + lane * 8);
            f16x8 h3 = *(const f16x8*)(Hf + (size_t)s3 * HC + lane * 8);
            const float a0 = exW[(j)     * 8 + head];
            const float a1 = exW[(j + 1) * 8 + head];
            const float a2 = exW[(j + 2) * 8 + head];
            const float a3 = exW[(j + 3) * 8 + head];
            #pragma unroll
            for (int c = 0; c < 8; ++c) {
                acc[c] = fmaf(a0, (float)h0[c], acc[c]);
                acc[c] = fmaf(a1, (float)h1[c], acc[c]);
                acc[c] = fmaf(a2, (float)h2[c], acc[c]);
                acc[c] = fmaf(a3, (float)h3[c], acc[c]);
            }
        }
        for (; j < cnt; ++j) {
            const int s = srcW[j];
            f16x8 hv = *(const f16x8*)(Hf + (size_t)s * HC + lane * 8);
            const float al = exW[j * 8 + head];
            #pragma unroll
            for (int c = 0; c < 8; ++c)
                acc[c] = fmaf(al, (float)hv[c], acc[c]);
        }
        __builtin_amdgcn_wave_barrier();
    }
    #pragma unroll
    for (int h = 0; h < 8; ++h)
        #pragma unroll
        for (int o = 1; o < 64; o <<= 1)
            ssum[h] += __shfl_xor(ssum[h], o);

    const float inv = 1.0f / (ssum[head] + 1e-16f);
    const float* bp = bias + lane * 8;
    float v[8];
    f16x8 ov;
    #pragma unroll
    for (int c = 0; c < 8; ++c) {
        v[c]  = acc[c] * inv + bp[c];
        ov[c] = (_Float16)v[c];
    }
    *(f16x8*)(out + (size_t)n * HC + lane * 8) = ov;

    // ---- fused BN stats: block reduce (4 waves -> 1) + shadow-copy atomics
    const int cp = blockIdx.x & (NCOPY - 1);
    __syncthreads();
    #pragma unroll
    for (int c = 0; c < 8; ++c) exW[lane * 8 + c] = v[c];
    __syncthreads();
    if (wv == 0) {
        #pragma unroll
        for (int c = 0; c < 8; ++c) {
            const int ch = lane * 8 + c;
            atomicAdd(&asum[cp * HC + ch],
                      exL[0][ch] + exL[1][ch] + exL[2][ch] + exL[3][ch]);
        }
    }
    __syncthreads();
    #pragma unroll
    for (int c = 0; c < 8; ++c) exW[lane * 8 + c] = v[c] * v[c];
    __syncthreads();
    if (wv == 0) {
        #pragma unroll
        for (int c = 0; c < 8; ++c) {
            const int ch = lane * 8 + c;
            atomicAdd(&asq[cp * HC + ch],
                      exL[0][ch] + exL[1][ch] + exL[2][ch] + exL[3][ch]);
        }
    }

    __threadfence();
    __shared__ int lastf;
    if (threadIdx.x == 0)
        lastf = (atomicAdd(ticket, 1) == AGG_BLKS - 1) ? 1 : 0;
    __syncthreads();
    if (!lastf) return;

    for (int ch = (int)threadIdx.x; ch < HC; ch += 256) {
        float S = 0.f, Q = 0.f;
        for (int p = 0; p < NCOPY; ++p) {
            S += atomicAdd(&asum[p * HC + ch], 0.0f);   // coherent readback
            Q += atomicAdd(&asq[p * HC + ch], 0.0f);
        }
        float mu  = S * invN;
        float var = Q * invN - mu * mu;
        float sc  = g[ch] / sqrtf(var + 1e-5f);
        scale[ch] = sc;
        shift[ch] = be[ch] - mu * sc;
    }
    if (threadIdx.x == 0) *ticket = 0;   // self-reset for graph replay
}

// NH=1 aggregate (layer 3) + fused BN stats; same structure, lane = channel
__global__ __launch_bounds__(256) void gat_aggregate1(
    const _Float16* __restrict__ Hf, const float* __restrict__ ssrc,
    const float* __restrict__ sdst, const int* __restrict__ off,
    const int* __restrict__ csr, const float* __restrict__ bias,
    float* __restrict__ out,
    float* __restrict__ asum, float* __restrict__ asq,
    const float* __restrict__ g, const float* __restrict__ be,
    float* __restrict__ scale, float* __restrict__ shift,
    float invN, int* __restrict__ ticket)
{
    const int wv   = threadIdx.x >> 6;
    const int lane = threadIdx.x & 63;
    const int n    = blockIdx.x * 4 + wv;

    __shared__ float exL[4][64];
    __shared__ int   srcL[4][64];
    float* exW  = exL[wv];
    int*   srcW = srcL[wv];

    const int e0 = off[n], e1 = off[n + 1];
    const float sd = sdst[n];

    float acc = 0.f, ssum = 0.f;
    for (int base = e0; base < e1; base += 64) {
        int cnt = e1 - base; if (cnt > 64) cnt = 64;
        if (lane < cnt) {
            int s = csr[base + lane];
            srcW[lane] = s;
            float l = ssrc[s] + sd;
            l = (l > 0.f) ? l : 0.2f * l;
            float ex = __expf(l);
            exW[lane] = ex;
            ssum += ex;
        }
        __builtin_amdgcn_wave_barrier();
        int j = 0;
        for (; j + 4 <= cnt; j += 4) {
            const int s0 = srcW[j],     s1 = srcW[j + 1];
            const int s2 = srcW[j + 2], s3 = srcW[j + 3];
            float h0 = (float)Hf[(size_t)s0 * 64 + lane];
            float h1 = (float)Hf[(size_t)s1 * 64 + lane];
            float h2 = (float)Hf[(size_t)s2 * 64 + lane];
            float h3 = (float)Hf[(size_t)s3 * 64 + lane];
            acc = fmaf(exW[j],     h0, acc);
            acc = fmaf(exW[j + 1], h1, acc);
            acc = fmaf(exW[j + 2], h2, acc);
            acc = fmaf(exW[j + 3], h3, acc);
        }
        for (; j < cnt; ++j)
            acc = fmaf(exW[j], (float)Hf[(size_t)srcW[j] * 64 + lane], acc);
        __builtin_amdgcn_wave_barrier();
    }
    #pragma unroll
    for (int o = 1; o < 64; o <<= 1)
        ssum += __shfl_xor(ssum, o);

    const float v = acc / (ssum + 1e-16f) + bias[lane];
    out[(size_t)n * 64 + lane] = v;

    // ---- fused BN stats
    const int cp = blockIdx.x & (NCOPY - 1);
    __syncthreads();
    exW[lane] = v;
    __syncthreads();
    if (wv == 0)
        atomicAdd(&asum[cp * CH + lane],
                  exL[0][lane] + exL[1][lane] + exL[2][lane] + exL[3][lane]);
    __syncthreads();
    exW[lane] = v * v;
    __syncthreads();
    if (wv == 0)
        atomicAdd(&asq[cp * CH + lane],
                  exL[0][lane] + exL[1][lane] + exL[2][lane] + exL[3][lane]);

    __threadfence();
    __shared__ int lastf;
    if (threadIdx.x == 0)
        lastf = (atomicAdd(ticket, 1) == AGG_BLKS - 1) ? 1 : 0;
    __syncthreads();
    if (!lastf) return;

    if (threadIdx.x < CH) {
        const int ch = threadIdx.x;
        float S = 0.f, Q = 0.f;
        for (int p = 0; p < NCOPY; ++p) {
            S += atomicAdd(&asum[p * CH + ch], 0.0f);
            Q += atomicAdd(&asq[p * CH + ch], 0.0f);
        }
        float mu  = S * invN;
        float var = Q * invN - mu * mu;
        float sc  = g[ch] / sqrtf(var + 1e-5f);
        scale[ch] = sc;
        shift[ch] = be[ch] - mu * sc;
    }
    if (threadIdx.x == 0) *ticket = 0;
}

// f16 in, f16 residual, f16 out: v = elu(x*scale + shift) + res  (16B/lane)
__global__ void bn_apply16(const _Float16* __restrict__ xin,
                           const _Float16* __restrict__ res,
                           const float* __restrict__ scale,
                           const float* __restrict__ shift,
                           _Float16* __restrict__ out, size_t total8)
{
    size_t i = (size_t)blockIdx.x * blockDim.x + threadIdx.x;
    if (i >= total8) return;
    int c = (int)((i * 8) & (size_t)(HC - 1));
    f16x8 xv = ((const f16x8*)xin)[i];
    f16x8 rv = ((const f16x8*)res)[i];
    float4 sa = *(const float4*)(scale + c);
    float4 sb = *(const float4*)(scale + c + 4);
    float4 ha = *(const float4*)(shift + c);
    float4 hb = *(const float4*)(shift + c + 4);
    float sc[8] = {sa.x, sa.y, sa.z, sa.w, sb.x, sb.y, sb.z, sb.w};
    float sh[8] = {ha.x, ha.y, ha.z, ha.w, hb.x, hb.y, hb.z, hb.w};
    f16x8 o;
    #pragma unroll
    for (int j = 0; j < 8; ++j) {
        float v = (float)xv[j] * sc[j] + sh[j];
        v = (v > 0.f) ? v : expm1f(v);
        o[j] = (_Float16)(v + (float)rv[j]);
    }
    ((f16x8*)out)[i] = o;
}

// ---------------------------------------------------------------------------
// Fused global-mean-pool + BN3 affine (affine commutes with mean) + linear
// ---------------------------------------------------------------------------
__global__ __launch_bounds__(256) void pool_linear(
    const float* __restrict__ x, const int* __restrict__ goff,
    const float* __restrict__ W, const float* __restrict__ b,
    const float* __restrict__ scale, const float* __restrict__ shift,
    float* __restrict__ out)
{
    const int g    = blockIdx.x;
    const int lane = threadIdx.x & 63;   // channel
    const int wave = threadIdx.x >> 6;   // 0..3
    const int r0 = goff[g], r1 = goff[g + 1];
    float s = 0.f;
    for (int r = r0 + wave; r < r1; r += 4)
        s += x[(size_t)r * CH + lane];
    __shared__ float red[4][CH];
    __shared__ float mean_l[CH];
    red[wave][lane] = s;
    __syncthreads();
    if (wave == 0) {
        float tot = red[0][lane] + red[1][lane] + red[2][lane] + red[3][lane];
        float cnt = (float)(r1 - r0);
        float m = tot / fmaxf(cnt, 1.0f);
        mean_l[lane] = m * scale[lane] + shift[lane];   // BN3 applied on mean
    }
    __syncthreads();
    if (threadIdx.x < NCLS) {
        const int j = threadIdx.x;
        float acc = b[j];
        for (int c = 0; c < CH; ++c)
            acc = fmaf(mean_l[c], W[c * NCLS + j], acc);
        out[g * NCLS + j] = acc;
    }
}

// ---------------------------------------------------------------------------
// Host launcher
// ---------------------------------------------------------------------------
extern "C" void kernel_launch(void* const* d_in, const int* in_sizes, int n_in,
                              void* d_out, int out_size, void* d_ws, size_t ws_size,
                              hipStream_t stream)
{
    const float* x_in  = (const float*)d_in[0];
    const int*   ei    = (const int*)  d_in[1];
    const int*   batch = (const int*)  d_in[2];
    const float* enc_W = (const float*)d_in[3];
    const float* enc_b = (const float*)d_in[4];
    const float* W1  = (const float*)d_in[5];
    const float* as1 = (const float*)d_in[6];
    const float* ad1 = (const float*)d_in[7];
    const float* b1  = (const float*)d_in[8];
    const float* g1  = (const float*)d_in[9];
    const float* be1 = (const float*)d_in[10];
    const float* W2  = (const float*)d_in[11];
    const float* as2 = (const float*)d_in[12];
    const float* ad2 = (const float*)d_in[13];
    const float* b2  = (const float*)d_in[14];
    const float* g2  = (const float*)d_in[15];
    const float* be2 = (const float*)d_in[16];
    const float* W3  = (const float*)d_in[17];
    const float* as3 = (const float*)d_in[18];
    const float* ad3 = (const float*)d_in[19];
    const float* b3  = (const float*)d_in[20];
    const float* g3  = (const float*)d_in[21];
    const float* be3 = (const float*)d_in[22];
    const float* linW = (const float*)d_in[23];
    const float* linb = (const float*)d_in[24];
    float* out = (float*)d_out;

    char* ws = (char*)d_ws;
    size_t off_b = 0;
    auto alloc = [&](size_t bytes) -> void* {
        void* p = ws + off_b;
        off_b = (off_b + bytes + 255) & ~(size_t)255;
        return p;
    };
    _Float16* f16A   = (_Float16*)alloc((size_t)MPAD * HC * 2);   // act buf A
    _Float16* f16B   = (_Float16*)alloc((size_t)MPAD * HC * 2);   // act buf B
    _Float16* H16    = (_Float16*)alloc((size_t)MPAD * HC * 2);   // GAT features
    _Float16* g16    = (_Float16*)alloc((size_t)NNODES * HC * 2); // aggregate out
    _Float16* h3_16  = (_Float16*)alloc((size_t)MPAD * CH * 2);
    float*    g3o    = (float*)alloc((size_t)NNODES * CH * 4);
    _Float16* encWt  = (_Float16*)alloc((size_t)HC * FIN * 2);
    _Float16* W1t    = (_Float16*)alloc((size_t)HC * HC * 2);
    _Float16* W2t    = (_Float16*)alloc((size_t)HC * HC * 2);
    _Float16* W3t    = (_Float16*)alloc((size_t)CH * HC * 2);
    float* ssrc   = (float*)alloc((size_t)MPAD * HEADS8 * 4);
    float* sdst   = (float*)alloc((size_t)MPAD * HEADS8 * 4);
    int*   deg    = (int*)  alloc((size_t)NNODES * 4);
    int*   offp   = (int*)  alloc((size_t)(NNODES + 1) * 4);
    int*   cursor = (int*)  alloc((size_t)NNODES * 4);
    int*   csr    = (int*)  alloc((size_t)EPLUS * 4);
    int*   goff   = (int*)  alloc((size_t)(NG + 1) * 4);
    float* bnacc  = (float*)alloc((size_t)BNACC_N * 4);
    float* bnsc   = (float*)alloc(HC * 4);
    float* bnsh   = (float*)alloc(HC * 4);
    int*   tickets= (int*)  alloc(4 * 4);

    // ---- Prep: histogram+goff, x fp16 convert, weight transposes (1 kernel)
    hipMemsetAsync(deg, 0, (size_t)NNODES * 4, stream);
    prep_all<<<PREP_CNT + PREP_CONV + 1024, 256, 0, stream>>>(
        ei, deg, batch, goff, x_in, f16A, enc_W, W1, W2, W3,
        encWt, W1t, W2t, W3t, tickets, bnacc);

    const int NB = (HC / 64) * (MPAD / 128);         // 632 GEMM blocks
    const int SCAT = (EPLUS + 255) / 256;            // 665 scatter blocks

    // ---- Encoder GEMM; tail block runs the degree exclusive-scan
    gemm_f16_mfma<<<NB + 1, 256, 0, stream>>>(
        f16A, encWt, enc_b, f16B, nullptr, nullptr, nullptr, nullptr,
        MPAD, HC, FIN, 1, deg, offp, cursor);

    const size_t total8 = (size_t)NNODES * HC / 8;
    const int apply_blocks = (int)((total8 + 255) / 256);
    const float invN = 1.0f / NNODES;

    // bnacc regions
    float* L1sum = bnacc;                 // NCOPY*512
    float* L1sq  = bnacc + 8192;
    float* L2sum = bnacc + 16384;
    float* L2sq  = bnacc + 24576;
    float* L3sum = bnacc + 32768;         // NCOPY*64
    float* L3sq  = bnacc + 33792;

    // ---- Layer 1: GEMM (+fused scores) with CSR scatter in tail blocks
    gemm_f16_mfma<<<NB + SCAT, 256, 0, stream>>>(
        f16B, W1t, nullptr, H16, ssrc, sdst, as1, ad1,
        MPAD, HC, HC, 2, ei, cursor, csr);
    gat_aggregate8<<<AGG_BLKS, 256, 0, stream>>>(
        H16, ssrc, sdst, offp, csr, b1, g16,
        L1sum, L1sq, g1, be1, bnsc, bnsh, invN, tickets + 0);
    bn_apply16<<<apply_blocks, 256, 0, stream>>>(g16, f16B, bnsc, bnsh,
                                                 f16A, total8);

    // ---- Layer 2
    gemm_f16_mfma<<<NB, 256, 0, stream>>>(
        f16A, W2t, nullptr, H16, ssrc, sdst, as2, ad2,
        MPAD, HC, HC, 0, nullptr, nullptr, nullptr);
    gat_aggregate8<<<AGG_BLKS, 256, 0, stream>>>(
        H16, ssrc, sdst, offp, csr, b2, g16,
        L2sum, L2sq, g2, be2, bnsc, bnsh, invN, tickets + 1);
    bn_apply16<<<apply_blocks, 256, 0, stream>>>(g16, f16A, bnsc, bnsh,
                                                 f16B, total8);

    // ---- Layer 3 (heads=1, C=64)
    gemm_f16_mfma_n64<<<MPAD / 64, 256, 0, stream>>>(f16B, W3t, h3_16,
                                                     ssrc, sdst, as3, ad3);
    gat_aggregate1<<<AGG_BLKS, 256, 0, stream>>>(
        h3_16, ssrc, sdst, offp, csr, b3, g3o,
        L3sum, L3sq, g3, be3, bnsc, bnsh, invN, tickets + 2);

    // ---- Fused pool + BN3 affine + final linear
    pool_linear<<<NG, 256, 0, stream>>>(g3o, goff, linW, linb, bnsc, bnsh,
                                        out);
}

// Round 4
// 477.037 us; speedup vs baseline: 1.9239x; 1.9239x over previous
//
#include <hip/hip_runtime.h>
#include <hip/hip_bf16.h>
#include <math.h>

// Problem constants (from reference)
#define NNODES 10000
#define MPAD   10112    // 79 * 128
#define EDGES  160000
#define EPLUS  170000   // EDGES + NNODES self-loops
#define FIN    512
#define HEADS8 8
#define CH     64
#define HC     512      // HEADS8*CH
#define NG     64       // graphs
#define NCLS   64
#define NSTAT  512      // bn stats blocks (f16 path)
#define NSTAT3 256      // bn stats blocks (layer-3 fp32 path)
#define NCOPY  16       // shadow copies; each (ch,copy) accumulator OWNS a 64B line

typedef _Float16 f16x8 __attribute__((ext_vector_type(8)));
typedef _Float16 f16x4 __attribute__((ext_vector_type(4)));
typedef _Float16 f16x2 __attribute__((ext_vector_type(2)));
typedef float    f32x4 __attribute__((ext_vector_type(4)));

#define GLD_LDS16(g, l)                                                        \
    __builtin_amdgcn_global_load_lds(                                          \
        (const __attribute__((address_space(1))) void*)(g),                    \
        (__attribute__((address_space(3))) void*)(l), 16, 0, 0)

// bnacc layout (floats; one accumulator per 16-float (64B) line):
//  L1sum @0        [512*256]   L1sq @131072 [512*256]
//  L2sum @262144   [512*256]   L2sq @393216 [512*256]
//  L3sum @524288   [64*256]    L3sq @540672 [64*256]
#define BNACC_N 557056

// ---------------------------------------------------------------------------
// Fused prep: [0,665) dst-degree histogram + graph offsets (+ bnacc zeroing);
//             [665,5665) fp32->fp16 convert of x_in;
//             [5665,...) 4 weight transposes (fp32 KxN -> fp16 NxK)
// ---------------------------------------------------------------------------
#define PREP_CNT  665
#define PREP_CONV 5000   // 10000*512/4 / 256
#define ZBLK      544    // 544*256 float4 = 557056 floats zeroed
__global__ void prep_all(const int* __restrict__ ei, int* __restrict__ deg,
                         const int* __restrict__ batch, int* __restrict__ goff,
                         const float* __restrict__ x_in, _Float16* __restrict__ x16,
                         const float* __restrict__ Wa, const float* __restrict__ Wb,
                         const float* __restrict__ Wc, const float* __restrict__ Wd,
                         _Float16* __restrict__ Ta, _Float16* __restrict__ Tb,
                         _Float16* __restrict__ Tc, _Float16* __restrict__ Td,
                         int* __restrict__ tickets, float* __restrict__ bnacc)
{
    const int b   = blockIdx.x;
    const int tid = threadIdx.x;
    if (b < PREP_CNT) {
        if (b == 0 && tid < 4) tickets[tid] = 0;
        if (b < ZBLK)
            ((float4*)bnacc)[b * 256 + tid] = make_float4(0.f, 0.f, 0.f, 0.f);
        int e = b * 256 + tid;
        if (e < NNODES) {
            int bb = batch[e];
            int bprev = (e == 0) ? -1 : batch[e - 1];
            for (int g = bprev + 1; g <= bb; ++g) goff[g] = e;
            if (e == NNODES - 1)
                for (int g = bb + 1; g <= NG; ++g) goff[g] = NNODES;
        }
        if (e >= EPLUS) return;
        int dst = (e < EDGES) ? ei[EDGES + e] : (e - EDGES);
        atomicAdd(&deg[dst], 1);
    } else if (b < PREP_CNT + PREP_CONV) {
        int i = (b - PREP_CNT) * 256 + tid;
        float4 v = ((const float4*)x_in)[i];
        f16x4 o;
        o[0] = (_Float16)v.x; o[1] = (_Float16)v.y;
        o[2] = (_Float16)v.z; o[3] = (_Float16)v.w;
        ((f16x4*)x16)[i] = o;
    } else {
        int tb = b - (PREP_CNT + PREP_CONV);
        int z  = tb >> 8;            // 0..3
        int rem = tb & 255;
        int bxi = rem & 15, byi = rem >> 4;
        if (z == 3 && bxi >= 2) return;   // W3 has only 64 cols
        const float* W = (z == 0) ? Wa : (z == 1) ? Wb : (z == 2) ? Wc : Wd;
        _Float16*    T = (z == 0) ? Ta : (z == 1) ? Tb : (z == 2) ? Tc : Td;
        const int ldW = (z == 3) ? 64 : 512;
        __shared__ float t[32][33];
        int bx = bxi * 32, by = byi * 32;
        int tx = tid & 31, ty = tid >> 5;   // 32 x 8
        #pragma unroll
        for (int i = 0; i < 32; i += 8)
            t[ty + i][tx] = W[(size_t)(by + ty + i) * ldW + bx + tx];
        __syncthreads();
        #pragma unroll
        for (int i = 0; i < 32; i += 8)
            T[(size_t)(bx + ty + i) * 512 + by + tx] = (_Float16)t[tx][ty + i];
    }
}

// ---------------------------------------------------------------------------
// Device-side exclusive scan of deg (tail block of the encoder GEMM launch)
// ---------------------------------------------------------------------------
__device__ void exscan_dev(const int* __restrict__ deg, int* __restrict__ off,
                           int* __restrict__ cursor, int* partial /* LDS[256] */)
{
    const int tid = threadIdx.x;
    const int chunk = (NNODES + 255) / 256; // 40
    int begin = tid * chunk;
    int end   = begin + chunk; if (end > NNODES) end = NNODES;
    if (begin > NNODES) begin = NNODES;
    int s = 0;
    for (int i = begin; i < end; ++i) s += deg[i];
    partial[tid] = s;
    __syncthreads();
    for (int o = 1; o < 256; o <<= 1) {
        int v = (tid >= o) ? partial[tid - o] : 0;
        __syncthreads();
        partial[tid] += v;
        __syncthreads();
    }
    int run = (tid > 0) ? partial[tid - 1] : 0;  // exclusive prefix
    for (int i = begin; i < end; ++i) {
        off[i] = run; cursor[i] = run; run += deg[i];
    }
    if (tid == 255) off[NNODES] = run; // == EPLUS
}

// ---------------------------------------------------------------------------
// fp16 MFMA GEMM: C[M,N] = A16[M,K] @ Bt16[N,K]^T (+bias), 128x64 tile.
// Optional fused per-head attention scores (64-col tile == one head).
// tail==1: exscan (1 extra block); tail==2: CSR scatter (665 extra blocks).
// ---------------------------------------------------------------------------
__global__ __launch_bounds__(256) void gemm_f16_mfma(
    const _Float16* __restrict__ A16, const _Float16* __restrict__ Bt16,
    const float* __restrict__ bias, _Float16* __restrict__ C16,
    float* __restrict__ ssrc, float* __restrict__ sdst,
    const float* __restrict__ a_s, const float* __restrict__ a_d,
    int Mt, int Nn, int K,
    int tail, const int* __restrict__ tp0, int* __restrict__ tp1,
    int* __restrict__ tp2)
{
    __shared__ _Float16 As[128 * 32] __attribute__((aligned(16)));
    __shared__ _Float16 Bs[64 * 32]  __attribute__((aligned(16)));
    __shared__ float sS[2][128];
    __shared__ float sD[2][128];
    const int tid  = threadIdx.x;
    const int ncols = Nn >> 6;
    const int nb    = ncols * (Mt >> 7);
    const int bid   = blockIdx.x;

    if (bid >= nb) {   // tail work, overlapped with the GEMM blocks
        if (tail == 1) {
            exscan_dev(tp0, tp1, tp2, (int*)As);
        } else if (tail == 2) {
            int e = (bid - nb) * 256 + tid;
            if (e < EPLUS) {
                int srcN, dstN;
                if (e < EDGES) { srcN = tp0[e]; dstN = tp0[EDGES + e]; }
                else           { srcN = dstN = e - EDGES; }
                int pos = atomicAdd(&tp1[dstN], 1);
                tp2[pos] = srcN;
            }
        }
        return;
    }

    const int bt   = bid % ncols;        // col tile (== head when Nn==512)
    const int row0 = (bid / ncols) * 128;
    const int col0 = bt * 64;
    const int wave = tid >> 6;
    const int lane = tid & 63;
    const int wy = wave >> 1, wx = wave & 1;

    const int lrow = lane >> 2;
    const int lk   = (lane & 3) * 8;

    f32x4 acc[4][2] = {};

    for (int k0 = 0; k0 < K; k0 += 32) {
        if (k0) __syncthreads();
        #pragma unroll
        for (int r = 0; r < 2; ++r) {
            const int chunk = r * 4 + wave;
            const int trow  = chunk * 16 + lrow;
            GLD_LDS16(A16 + (size_t)(row0 + trow) * K + k0 + lk,
                      &As[chunk * 512]);
        }
        {
            const int trow = wave * 16 + lrow;
            GLD_LDS16(Bt16 + (size_t)(col0 + trow) * K + k0 + lk,
                      &Bs[wave * 512]);
        }
        __syncthreads();

        const int quad = lane >> 4;
        const int l16  = lane & 15;
        f16x8 af[4], bf[2];
        #pragma unroll
        for (int m = 0; m < 4; ++m)
            af[m] = *(const f16x8*)&As[(wy * 64 + m * 16 + l16) * 32 + quad * 8];
        #pragma unroll
        for (int n = 0; n < 2; ++n)
            bf[n] = *(const f16x8*)&Bs[(wx * 32 + n * 16 + l16) * 32 + quad * 8];
        #pragma unroll
        for (int m = 0; m < 4; ++m)
            #pragma unroll
            for (int n = 0; n < 2; ++n)
                acc[m][n] = __builtin_amdgcn_mfma_f32_16x16x32_f16(
                    af[m], bf[n], acc[m][n], 0, 0, 0);
    }

    const int quad = lane >> 4;
    const int l16  = lane & 15;
    #pragma unroll
    for (int m = 0; m < 4; ++m) {
        #pragma unroll
        for (int n = 0; n < 2; ++n) {
            const int col = col0 + wx * 32 + n * 16 + l16;
            const float bv = bias ? bias[col] : 0.0f;
            #pragma unroll
            for (int r = 0; r < 4; ++r) {
                const int row = row0 + wy * 64 + m * 16 + quad * 4 + r;
                C16[(size_t)row * Nn + col] = (_Float16)(acc[m][n][r] + bv);
            }
        }
    }

    if (ssrc) {   // fused per-head scores (bias-less layer GEMMs)
        float a_sv[2], a_dv[2];
        #pragma unroll
        for (int n = 0; n < 2; ++n) {
            const int col = col0 + wx * 32 + n * 16 + l16;
            a_sv[n] = a_s[col & 511];
            a_dv[n] = a_d[col & 511];
        }
        #pragma unroll
        for (int m = 0; m < 4; ++m) {
            #pragma unroll
            for (int r = 0; r < 4; ++r) {
                float vs = acc[m][0][r] * a_sv[0] + acc[m][1][r] * a_sv[1];
                float vd = acc[m][0][r] * a_dv[0] + acc[m][1][r] * a_dv[1];
                vs += __shfl_xor(vs, 1); vs += __shfl_xor(vs, 2);
                vs += __shfl_xor(vs, 4); vs += __shfl_xor(vs, 8);
                vd += __shfl_xor(vd, 1); vd += __shfl_xor(vd, 2);
                vd += __shfl_xor(vd, 4); vd += __shfl_xor(vd, 8);
                if (l16 == 0) {
                    const int lr = wy * 64 + m * 16 + quad * 4 + r;
                    sS[wx][lr] = vs;
                    sD[wx][lr] = vd;
                }
            }
        }
        __syncthreads();
        if (wx == 0 && l16 == 0) {
            const int head = bt;   // Nn==512: col tile == head
            #pragma unroll
            for (int m = 0; m < 4; ++m)
                #pragma unroll
                for (int r = 0; r < 4; ++r) {
                    const int lr = wy * 64 + m * 16 + quad * 4 + r;
                    const int row = row0 + lr;
                    ssrc[(size_t)row * HEADS8 + head] = sS[0][lr] + sS[1][lr];
                    sdst[(size_t)row * HEADS8 + head] = sD[0][lr] + sD[1][lr];
                }
        }
    }
}

// ---------------------------------------------------------------------------
// fp16 MFMA GEMM, N=64 (layer 3) with fused NH=1 scores. Padded rows.
// ---------------------------------------------------------------------------
__global__ __launch_bounds__(256) void gemm_f16_mfma_n64(
    const _Float16* __restrict__ A16, const _Float16* __restrict__ Bt16,
    _Float16* __restrict__ C16,
    float* __restrict__ ssrc, float* __restrict__ sdst,
    const float* __restrict__ a_s, const float* __restrict__ a_d)
{
    __shared__ _Float16 As[64 * 32] __attribute__((aligned(16)));
    __shared__ _Float16 Bs[64 * 32] __attribute__((aligned(16)));
    __shared__ float sS[2][64];
    __shared__ float sD[2][64];
    const int tid  = threadIdx.x;
    const int wave = tid >> 6;
    const int lane = tid & 63;
    const int row0 = blockIdx.x * 64;
    const int wy = wave >> 1, wx = wave & 1;

    const int lrow = lane >> 2;
    const int lk   = (lane & 3) * 8;

    f32x4 acc[2][2] = {};

    for (int k0 = 0; k0 < 512; k0 += 32) {
        if (k0) __syncthreads();
        {
            const int trow = wave * 16 + lrow;
            GLD_LDS16(A16 + (size_t)(row0 + trow) * 512 + k0 + lk, &As[wave * 512]);
            GLD_LDS16(Bt16 + (size_t)trow * 512 + k0 + lk, &Bs[wave * 512]);
        }
        __syncthreads();

        const int quad = lane >> 4;
        const int l16  = lane & 15;
        f16x8 af[2], bf[2];
        #pragma unroll
        for (int m = 0; m < 2; ++m)
            af[m] = *(const f16x8*)&As[(wy * 32 + m * 16 + l16) * 32 + quad * 8];
        #pragma unroll
        for (int n = 0; n < 2; ++n)
            bf[n] = *(const f16x8*)&Bs[(wx * 32 + n * 16 + l16) * 32 + quad * 8];
        #pragma unroll
        for (int m = 0; m < 2; ++m)
            #pragma unroll
            for (int n = 0; n < 2; ++n)
                acc[m][n] = __builtin_amdgcn_mfma_f32_16x16x32_f16(
                    af[m], bf[n], acc[m][n], 0, 0, 0);
    }

    const int quad = lane >> 4;
    const int l16  = lane & 15;
    #pragma unroll
    for (int m = 0; m < 2; ++m)
        #pragma unroll
        for (int n = 0; n < 2; ++n) {
            const int col = wx * 32 + n * 16 + l16;
            #pragma unroll
            for (int r = 0; r < 4; ++r) {
                const int row = row0 + wy * 32 + m * 16 + quad * 4 + r;
                C16[(size_t)row * 64 + col] = (_Float16)acc[m][n][r];
            }
        }

    // fused scores (heads=1)
    {
        float a_sv[2], a_dv[2];
        #pragma unroll
        for (int n = 0; n < 2; ++n) {
            const int col = wx * 32 + n * 16 + l16;
            a_sv[n] = a_s[col];
            a_dv[n] = a_d[col];
        }
        #pragma unroll
        for (int m = 0; m < 2; ++m)
            #pragma unroll
            for (int r = 0; r < 4; ++r) {
                float vs = acc[m][0][r] * a_sv[0] + acc[m][1][r] * a_sv[1];
                float vd = acc[m][0][r] * a_dv[0] + acc[m][1][r] * a_dv[1];
                vs += __shfl_xor(vs, 1); vs += __shfl_xor(vs, 2);
                vs += __shfl_xor(vs, 4); vs += __shfl_xor(vs, 8);
                vd += __shfl_xor(vd, 1); vd += __shfl_xor(vd, 2);
                vd += __shfl_xor(vd, 4); vd += __shfl_xor(vd, 8);
                if (l16 == 0) {
                    const int lr = wy * 32 + m * 16 + quad * 4 + r;
                    sS[wx][lr] = vs;
                    sD[wx][lr] = vd;
                }
            }
        __syncthreads();
        if (wx == 0 && l16 == 0) {
            #pragma unroll
            for (int m = 0; m < 2; ++m)
                #pragma unroll
                for (int r = 0; r < 4; ++r) {
                    const int lr = wy * 32 + m * 16 + quad * 4 + r;
                    const int row = row0 + lr;
                    ssrc[row] = sS[0][lr] + sS[1][lr];
                    sdst[row] = sD[0][lr] + sD[1][lr];
                }
        }
    }
}

// ---------------------------------------------------------------------------
// Segment-softmax aggregation, NH=8 fp16, single pass; f16 output.
// (round-2 proven version: 1 node per 64-thread block)
// ---------------------------------------------------------------------------
__global__ __launch_bounds__(64) void gat_aggregate8(
    const _Float16* __restrict__ Hf, const float* __restrict__ ssrc,
    const float* __restrict__ sdst, const int* __restrict__ off,
    const int* __restrict__ csr, const float* __restrict__ bias,
    _Float16* __restrict__ out)
{
    const int n    = blockIdx.x;
    const int lane = threadIdx.x;
    const int head = lane >> 3;
    const int e0 = off[n], e1 = off[n + 1];

    float4 sd0 = ((const float4*)(sdst + n * 8))[0];
    float4 sd1 = ((const float4*)(sdst + n * 8))[1];
    float sd[8] = {sd0.x, sd0.y, sd0.z, sd0.w, sd1.x, sd1.y, sd1.z, sd1.w};

    __shared__ float exL[64 * 8];
    __shared__ int   srcL[64];
    float acc[8]  = {};
    float ssum[8] = {};
    for (int base = e0; base < e1; base += 64) {
        int cnt = e1 - base; if (cnt > 64) cnt = 64;
        if (lane < cnt) {
            int s = csr[base + lane];
            srcL[lane] = s;
            float4 s0 = ((const float4*)(ssrc + s * 8))[0];
            float4 s1 = ((const float4*)(ssrc + s * 8))[1];
            float lv[8] = {s0.x, s0.y, s0.z, s0.w, s1.x, s1.y, s1.z, s1.w};
            #pragma unroll
            for (int h = 0; h < 8; ++h) {
                float l = lv[h] + sd[h];
                l = (l > 0.f) ? l : 0.2f * l;
                float ex = __expf(l);
                exL[lane * 8 + h] = ex;
                ssum[h] += ex;
            }
        }
        __syncthreads();
        int j = 0;
        for (; j + 4 <= cnt; j += 4) {
            const int s0 = srcL[j],     s1 = srcL[j + 1];
            const int s2 = srcL[j + 2], s3 = srcL[j + 3];
            f16x8 h0 = *(const f16x8*)(Hf + (size_t)s0 * HC + lane * 8);
            f16x8 h1 = *(const f16x8*)(Hf + (size_t)s1 * HC + lane * 8);
            f16x8 h2 = *(const f16x8*)(Hf + (size_t)s2 * HC + lane * 8);
            f16x8 h3 = *(const f16x8*)(Hf + (size_t)s3 * HC + lane * 8);
            const float a0 = exL[(j)     * 8 + head];
            const float a1 = exL[(j + 1) * 8 + head];
            const float a2 = exL[(j + 2) * 8 + head];
            const float a3 = exL[(j + 3) * 8 + head];
            #pragma unroll
            for (int c = 0; c < 8; ++c) {
                acc[c] = fmaf(a0, (float)h0[c], acc[c]);
                acc[c] = fmaf(a1, (float)h1[c], acc[c]);
                acc[c] = fmaf(a2, (float)h2[c], acc[c]);
                acc[c] = fmaf(a3, (float)h3[c], acc[c]);
            }
        }
        for (; j < cnt; ++j) {
            const int s = srcL[j];
            f16x8 hv = *(const f16x8*)(Hf + (size_t)s * HC + lane * 8);
            const float al = exL[j * 8 + head];
            #pragma unroll
            for (int c = 0; c < 8; ++c)
                acc[c] = fmaf(al, (float)hv[c], acc[c]);
        }
        __syncthreads();
    }
    #pragma unroll
    for (int h = 0; h < 8; ++h)
        #pragma unroll
        for (int o = 1; o < 64; o <<= 1)
            ssum[h] += __shfl_xor(ssum[h], o);

    const float inv = 1.0f / (ssum[head] + 1e-16f);
    const float* bp = bias + lane * 8;
    f16x8 ov;
    #pragma unroll
    for (int c = 0; c < 8; ++c)
        ov[c] = (_Float16)(acc[c] * inv + bp[c]);
    *(f16x8*)(out + (size_t)n * HC + lane * 8) = ov;
}

// NH=1 fp16 aggregate (layer 3), single pass, lane = channel; unrolled x4
__global__ __launch_bounds__(64) void gat_aggregate1(
    const _Float16* __restrict__ Hf, const float* __restrict__ ssrc,
    const float* __restrict__ sdst, const int* __restrict__ off,
    const int* __restrict__ csr, const float* __restrict__ bias,
    float* __restrict__ out)
{
    const int n    = blockIdx.x;
    const int lane = threadIdx.x;
    const int e0 = off[n], e1 = off[n + 1];
    const float sd = sdst[n];

    __shared__ float exL[64];
    __shared__ int   srcL[64];
    float acc = 0.f, ssum = 0.f;
    for (int base = e0; base < e1; base += 64) {
        int cnt = e1 - base; if (cnt > 64) cnt = 64;
        if (lane < cnt) {
            int s = csr[base + lane];
            srcL[lane] = s;
            float l = ssrc[s] + sd;
            l = (l > 0.f) ? l : 0.2f * l;
            float ex = __expf(l);
            exL[lane] = ex;
            ssum += ex;
        }
        __syncthreads();
        int j = 0;
        for (; j + 4 <= cnt; j += 4) {
            const int s0 = srcL[j],     s1 = srcL[j + 1];
            const int s2 = srcL[j + 2], s3 = srcL[j + 3];
            float h0 = (float)Hf[(size_t)s0 * 64 + lane];
            float h1 = (float)Hf[(size_t)s1 * 64 + lane];
            float h2 = (float)Hf[(size_t)s2 * 64 + lane];
            float h3 = (float)Hf[(size_t)s3 * 64 + lane];
            acc = fmaf(exL[j],     h0, acc);
            acc = fmaf(exL[j + 1], h1, acc);
            acc = fmaf(exL[j + 2], h2, acc);
            acc = fmaf(exL[j + 3], h3, acc);
        }
        for (; j < cnt; ++j)
            acc = fmaf(exL[j], (float)Hf[(size_t)srcL[j] * 64 + lane], acc);
        __syncthreads();
    }
    #pragma unroll
    for (int o = 1; o < 64; o <<= 1)
        ssum += __shfl_xor(ssum, o);

    out[(size_t)n * 64 + lane] = acc / (ssum + 1e-16f) + bias[lane];
}

// ---------------------------------------------------------------------------
// BatchNorm stats (f16), BW-bound: 512 blocks, wave-per-row f16x8 loads,
// block LDS reduce, line-exclusive atomics (one accumulator per 64B line,
// serial chain = NSTAT/NCOPY = 32 line-RMWs), last-block ticket finalize.
// ---------------------------------------------------------------------------
__global__ __launch_bounds__(256) void bn_stats_f16(
    const _Float16* __restrict__ x, int rows,
    float* __restrict__ asum, float* __restrict__ asq,
    const float* __restrict__ g, const float* __restrict__ be,
    float* __restrict__ scale, float* __restrict__ shift,
    float invN, int* __restrict__ ticket)
{
    const int t    = threadIdx.x;
    const int lane = t & 63;
    const int wv   = t >> 6;
    float s[8] = {}, q[8] = {};
    for (int r = blockIdx.x * 4 + wv; r < rows; r += NSTAT * 4) {
        f16x8 v = *(const f16x8*)(x + (size_t)r * HC + lane * 8);
        #pragma unroll
        for (int j = 0; j < 8; ++j) {
            float f = (float)v[j];
            s[j] += f; q[j] += f * f;
        }
    }
    __shared__ float ls[4][HC];
    __shared__ float lq[4][HC];
    #pragma unroll
    for (int j = 0; j < 8; ++j) {
        ls[wv][lane * 8 + j] = s[j];
        lq[wv][lane * 8 + j] = q[j];
    }
    __syncthreads();
    const int cp = blockIdx.x & (NCOPY - 1);
    if (wv == 0) {
        #pragma unroll
        for (int j = 0; j < 8; ++j) {
            const int ch = lane * 8 + j;
            atomicAdd(&asum[ch * 256 + cp * 16],
                      ls[0][ch] + ls[1][ch] + ls[2][ch] + ls[3][ch]);
        }
    } else if (wv == 1) {
        #pragma unroll
        for (int j = 0; j < 8; ++j) {
            const int ch = lane * 8 + j;
            atomicAdd(&asq[ch * 256 + cp * 16],
                      lq[0][ch] + lq[1][ch] + lq[2][ch] + lq[3][ch]);
        }
    }
    __syncthreads();          // drains outstanding atomics (vmcnt) + barrier
    __threadfence();
    __shared__ int lastf;
    if (t == 0) lastf = (atomicAdd(ticket, 1) == NSTAT - 1) ? 1 : 0;
    __syncthreads();
    if (!lastf) return;

    for (int ch = t; ch < HC; ch += 256) {
        float S = 0.f, Q = 0.f;
        for (int p = 0; p < NCOPY; ++p) {
            S += atomicAdd(&asum[ch * 256 + p * 16], 0.0f);   // coherent readback
            Q += atomicAdd(&asq[ch * 256 + p * 16], 0.0f);
        }
        float mu  = S * invN;
        float var = Q * invN - mu * mu;
        float sc  = g[ch] / sqrtf(var + 1e-5f);
        scale[ch] = sc;
        shift[ch] = be[ch] - mu * sc;
    }
    if (t == 0) *ticket = 0;                   // self-reset for graph replay
}

// fp32 stats (layer 3, cols=64), float4 loads, same line-exclusive atomics
__global__ __launch_bounds__(256) void bn_stats3(
    const float* __restrict__ x,
    float* __restrict__ asum, float* __restrict__ asq,
    const float* __restrict__ g, const float* __restrict__ be,
    float* __restrict__ scale, float* __restrict__ shift,
    float invN, int* __restrict__ ticket)
{
    const int t    = threadIdx.x;
    const int c4   = (t & 15) * 4;  // 4 cols; 16 threads cover a 256B row
    const int rsub = t >> 4;        // 0..15: 16 rows in flight per block
    float s[4] = {}, q[4] = {};
    for (int r = blockIdx.x * 16 + rsub; r < NNODES; r += NSTAT3 * 16) {
        float4 v = *(const float4*)(x + (size_t)r * CH + c4);
        s[0] += v.x; q[0] += v.x * v.x;
        s[1] += v.y; q[1] += v.y * v.y;
        s[2] += v.z; q[2] += v.z * v.z;
        s[3] += v.w; q[3] += v.w * v.w;
    }
    __shared__ float ls[16][CH];
    __shared__ float lq[16][CH];
    #pragma unroll
    for (int j = 0; j < 4; ++j) {
        ls[rsub][c4 + j] = s[j];
        lq[rsub][c4 + j] = q[j];
    }
    __syncthreads();
    const int cp = blockIdx.x & (NCOPY - 1);
    if (t < CH) {
        float tot = 0.f;
        #pragma unroll
        for (int p = 0; p < 16; ++p) tot += ls[p][t];
        atomicAdd(&asum[t * 256 + cp * 16], tot);
    } else if (t < 2 * CH) {
        const int ch = t - CH;
        float tot = 0.f;
        #pragma unroll
        for (int p = 0; p < 16; ++p) tot += lq[p][ch];
        atomicAdd(&asq[ch * 256 + cp * 16], tot);
    }
    __syncthreads();
    __threadfence();
    __shared__ int lastf;
    if (t == 0) lastf = (atomicAdd(ticket, 1) == NSTAT3 - 1) ? 1 : 0;
    __syncthreads();
    if (!lastf) return;

    if (t < CH) {
        float S = 0.f, Q = 0.f;
        for (int p = 0; p < NCOPY; ++p) {
            S += atomicAdd(&asum[t * 256 + p * 16], 0.0f);
            Q += atomicAdd(&asq[t * 256 + p * 16], 0.0f);
        }
        float mu  = S * invN;
        float var = Q * invN - mu * mu;
        float sc  = g[t] / sqrtf(var + 1e-5f);
        scale[t] = sc;
        shift[t] = be[t] - mu * sc;
    }
    if (t == 0) *ticket = 0;
}

// f16 in, f16 residual, f16 out: v = elu(x*scale + shift) + res  (16B/lane)
__global__ void bn_apply16(const _Float16* __restrict__ xin,
                           const _Float16* __restrict__ res,
                           const float* __restrict__ scale,
                           const float* __restrict__ shift,
                           _Float16* __restrict__ out, size_t total8)
{
    size_t i = (size_t)blockIdx.x * blockDim.x + threadIdx.x;
    if (i >= total8) return;
    int c = (int)((i * 8) & (size_t)(HC - 1));
    f16x8 xv = ((const f16x8*)xin)[i];
    f16x8 rv = ((const f16x8*)res)[i];
    float4 sa = *(const float4*)(scale + c);
    float4 sb = *(const float4*)(scale + c + 4);
    float4 ha = *(const float4*)(shift + c);
    float4 hb = *(const float4*)(shift + c + 4);
    float sc[8] = {sa.x, sa.y, sa.z, sa.w, sb.x, sb.y, sb.z, sb.w};
    float sh[8] = {ha.x, ha.y, ha.z, ha.w, hb.x, hb.y, hb.z, hb.w};
    f16x8 o;
    #pragma unroll
    for (int j = 0; j < 8; ++j) {
        float v = (float)xv[j] * sc[j] + sh[j];
        v = (v > 0.f) ? v : expm1f(v);
        o[j] = (_Float16)(v + (float)rv[j]);
    }
    ((f16x8*)out)[i] = o;
}

// ---------------------------------------------------------------------------
// Fused global-mean-pool + BN3 affine (affine commutes with mean) + linear
// ---------------------------------------------------------------------------
__global__ __launch_bounds__(256) void pool_linear(
    const float* __restrict__ x, const int* __restrict__ goff,
    const float* __restrict__ W, const float* __restrict__ b,
    const float* __restrict__ scale, const float* __restrict__ shift,
    float* __restrict__ out)
{
    const int g    = blockIdx.x;
    const int lane = threadIdx.x & 63;   // channel
    const int wave = threadIdx.x >> 6;   // 0..3
    const int r0 = goff[g], r1 = goff[g + 1];
    float s = 0.f;
    for (int r = r0 + wave; r < r1; r += 4)
        s += x[(size_t)r * CH + lane];
    __shared__ float red[4][CH];
    __shared__ float mean_l[CH];
    red[wave][lane] = s;
    __syncthreads();
    if (wave == 0) {
        float tot = red[0][lane] + red[1][lane] + red[2][lane] + red[3][lane];
        float cnt = (float)(r1 - r0);
        float m = tot / fmaxf(cnt, 1.0f);
        mean_l[lane] = m * scale[lane] + shift[lane];   // BN3 applied on mean
    }
    __syncthreads();
    if (threadIdx.x < NCLS) {
        const int j = threadIdx.x;
        float acc = b[j];
        for (int c = 0; c < CH; ++c)
            acc = fmaf(mean_l[c], W[c * NCLS + j], acc);
        out[g * NCLS + j] = acc;
    }
}

// ---------------------------------------------------------------------------
// Host launcher
// ---------------------------------------------------------------------------
extern "C" void kernel_launch(void* const* d_in, const int* in_sizes, int n_in,
                              void* d_out, int out_size, void* d_ws, size_t ws_size,
                              hipStream_t stream)
{
    const float* x_in  = (const float*)d_in[0];
    const int*   ei    = (const int*)  d_in[1];
    const int*   batch = (const int*)  d_in[2];
    const float* enc_W = (const float*)d_in[3];
    const float* enc_b = (const float*)d_in[4];
    const float* W1  = (const float*)d_in[5];
    const float* as1 = (const float*)d_in[6];
    const float* ad1 = (const float*)d_in[7];
    const float* b1  = (const float*)d_in[8];
    const float* g1  = (const float*)d_in[9];
    const float* be1 = (const float*)d_in[10];
    const float* W2  = (const float*)d_in[11];
    const float* as2 = (const float*)d_in[12];
    const float* ad2 = (const float*)d_in[13];
    const float* b2  = (const float*)d_in[14];
    const float* g2  = (const float*)d_in[15];
    const float* be2 = (const float*)d_in[16];
    const float* W3  = (const float*)d_in[17];
    const float* as3 = (const float*)d_in[18];
    const float* ad3 = (const float*)d_in[19];
    const float* b3  = (const float*)d_in[20];
    const float* g3  = (const float*)d_in[21];
    const float* be3 = (const float*)d_in[22];
    const float* linW = (const float*)d_in[23];
    const float* linb = (const float*)d_in[24];
    float* out = (float*)d_out;

    char* ws = (char*)d_ws;
    size_t off_b = 0;
    auto alloc = [&](size_t bytes) -> void* {
        void* p = ws + off_b;
        off_b = (off_b + bytes + 255) & ~(size_t)255;
        return p;
    };
    _Float16* f16A   = (_Float16*)alloc((size_t)MPAD * HC * 2);   // act buf A
    _Float16* f16B   = (_Float16*)alloc((size_t)MPAD * HC * 2);   // act buf B
    _Float16* H16    = (_Float16*)alloc((size_t)MPAD * HC * 2);   // GAT features
    _Float16* g16    = (_Float16*)alloc((size_t)NNODES * HC * 2); // aggregate out
    _Float16* h3_16  = (_Float16*)alloc((size_t)MPAD * CH * 2);
    float*    g3o    = (float*)alloc((size_t)NNODES * CH * 4);
    _Float16* encWt  = (_Float16*)alloc((size_t)HC * FIN * 2);
    _Float16* W1t    = (_Float16*)alloc((size_t)HC * HC * 2);
    _Float16* W2t    = (_Float16*)alloc((size_t)HC * HC * 2);
    _Float16* W3t    = (_Float16*)alloc((size_t)CH * HC * 2);
    float* ssrc   = (float*)alloc((size_t)MPAD * HEADS8 * 4);
    float* sdst   = (float*)alloc((size_t)MPAD * HEADS8 * 4);
    int*   deg    = (int*)  alloc((size_t)NNODES * 4);
    int*   offp   = (int*)  alloc((size_t)(NNODES + 1) * 4);
    int*   cursor = (int*)  alloc((size_t)NNODES * 4);
    int*   csr    = (int*)  alloc((size_t)EPLUS * 4);
    int*   goff   = (int*)  alloc((size_t)(NG + 1) * 4);
    float* bnacc  = (float*)alloc((size_t)BNACC_N * 4);
    float* bnsc   = (float*)alloc(HC * 4);
    float* bnsh   = (float*)alloc(HC * 4);
    int*   tickets= (int*)  alloc(4 * 4);

    // ---- Prep: histogram+goff, x fp16 convert, weight transposes (1 kernel)
    hipMemsetAsync(deg, 0, (size_t)NNODES * 4, stream);
    prep_all<<<PREP_CNT + PREP_CONV + 1024, 256, 0, stream>>>(
        ei, deg, batch, goff, x_in, f16A, enc_W, W1, W2, W3,
        encWt, W1t, W2t, W3t, tickets, bnacc);

    const int NB = (HC / 64) * (MPAD / 128);         // 632 GEMM blocks
    const int SCAT = (EPLUS + 255) / 256;            // 665 scatter blocks

    // ---- Encoder GEMM; tail block runs the degree exclusive-scan
    gemm_f16_mfma<<<NB + 1, 256, 0, stream>>>(
        f16A, encWt, enc_b, f16B, nullptr, nullptr, nullptr, nullptr,
        MPAD, HC, FIN, 1, deg, offp, cursor);

    const size_t total8 = (size_t)NNODES * HC / 8;
    const int apply_blocks = (int)((total8 + 255) / 256);
    const float invN = 1.0f / NNODES;

    // bnacc regions (line-exclusive accumulators)
    float* L1sum = bnacc;
    float* L1sq  = bnacc + 131072;
    float* L2sum = bnacc + 262144;
    float* L2sq  = bnacc + 393216;
    float* L3sum = bnacc + 524288;
    float* L3sq  = bnacc + 540672;

    // ---- Layer 1: GEMM (+fused scores) with CSR scatter in tail blocks
    gemm_f16_mfma<<<NB + SCAT, 256, 0, stream>>>(
        f16B, W1t, nullptr, H16, ssrc, sdst, as1, ad1,
        MPAD, HC, HC, 2, ei, cursor, csr);
    gat_aggregate8<<<NNODES, 64, 0, stream>>>(H16, ssrc, sdst, offp, csr,
                                              b1, g16);
    bn_stats_f16<<<NSTAT, 256, 0, stream>>>(g16, NNODES, L1sum, L1sq,
                                            g1, be1, bnsc, bnsh, invN,
                                            tickets + 0);
    bn_apply16<<<apply_blocks, 256, 0, stream>>>(g16, f16B, bnsc, bnsh,
                                                 f16A, total8);

    // ---- Layer 2
    gemm_f16_mfma<<<NB, 256, 0, stream>>>(
        f16A, W2t, nullptr, H16, ssrc, sdst, as2, ad2,
        MPAD, HC, HC, 0, nullptr, nullptr, nullptr);
    gat_aggregate8<<<NNODES, 64, 0, stream>>>(H16, ssrc, sdst, offp, csr,
                                              b2, g16);
    bn_stats_f16<<<NSTAT, 256, 0, stream>>>(g16, NNODES, L2sum, L2sq,
                                            g2, be2, bnsc, bnsh, invN,
                                            tickets + 1);
    bn_apply16<<<apply_blocks, 256, 0, stream>>>(g16, f16A, bnsc, bnsh,
                                                 f16B, total8);

    // ---- Layer 3 (heads=1, C=64)
    gemm_f16_mfma_n64<<<MPAD / 64, 256, 0, stream>>>(f16B, W3t, h3_16,
                                                     ssrc, sdst, as3, ad3);
    gat_aggregate1<<<NNODES, 64, 0, stream>>>(h3_16, ssrc, sdst, offp, csr,
                                              b3, g3o);
    bn_stats3<<<NSTAT3, 256, 0, stream>>>(g3o, L3sum, L3sq, g3, be3,
                                          bnsc, bnsh, invN, tickets + 2);

    // ---- Fused pool + BN3 affine + final linear
    pool_linear<<<NG, 256, 0, stream>>>(g3o, goff, linW, linb, bnsc, bnsh,
                                        out);
}

// Round 5
// 408.106 us; speedup vs baseline: 2.2488x; 1.1689x over previous
//
#include <hip/hip_runtime.h>
#include <hip/hip_bf16.h>
#include <math.h>

// Problem constants (from reference)
#define NNODES 10000
#define MPAD   10112    // 79 * 128
#define EDGES  160000
#define EPLUS  170000   // EDGES + NNODES self-loops
#define FIN    512
#define HEADS8 8
#define CH     64
#define HC     512      // HEADS8*CH
#define NG     64       // graphs
#define NCLS   64
#define NSTAT  128      // bn stats blocks (f16 path) -> 512 waves
#define NSTAT3 64       // bn stats blocks (layer-3 fp32 path)

typedef _Float16 f16x8 __attribute__((ext_vector_type(8)));
typedef _Float16 f16x4 __attribute__((ext_vector_type(4)));
typedef _Float16 f16x2 __attribute__((ext_vector_type(2)));
typedef float    f32x4 __attribute__((ext_vector_type(4)));

#define GLD_LDS16(g, l)                                                        \
    __builtin_amdgcn_global_load_lds(                                          \
        (const __attribute__((address_space(1))) void*)(g),                    \
        (__attribute__((address_space(3))) void*)(l), 16, 0, 0)

// ---------------------------------------------------------------------------
// Fused prep: [0,665) dst-degree histogram + graph offsets;
//             [665,5665) fp32->fp16 convert of x_in;
//             [5665,...) 4 weight transposes (fp32 KxN -> fp16 NxK)
// Partial-sum buffers need NO zeroing (plain stores overwrite them fully).
// ---------------------------------------------------------------------------
#define PREP_CNT  665
#define PREP_CONV 5000   // 10000*512/4 / 256
__global__ void prep_all(const int* __restrict__ ei, int* __restrict__ deg,
                         const int* __restrict__ batch, int* __restrict__ goff,
                         const float* __restrict__ x_in, _Float16* __restrict__ x16,
                         const float* __restrict__ Wa, const float* __restrict__ Wb,
                         const float* __restrict__ Wc, const float* __restrict__ Wd,
                         _Float16* __restrict__ Ta, _Float16* __restrict__ Tb,
                         _Float16* __restrict__ Tc, _Float16* __restrict__ Td,
                         int* __restrict__ tickets)
{
    const int b   = blockIdx.x;
    const int tid = threadIdx.x;
    if (b < PREP_CNT) {
        if (b == 0 && tid < 4) tickets[tid] = 0;
        int e = b * 256 + tid;
        if (e < NNODES) {
            int bb = batch[e];
            int bprev = (e == 0) ? -1 : batch[e - 1];
            for (int g = bprev + 1; g <= bb; ++g) goff[g] = e;
            if (e == NNODES - 1)
                for (int g = bb + 1; g <= NG; ++g) goff[g] = NNODES;
        }
        if (e >= EPLUS) return;
        int dst = (e < EDGES) ? ei[EDGES + e] : (e - EDGES);
        atomicAdd(&deg[dst], 1);
    } else if (b < PREP_CNT + PREP_CONV) {
        int i = (b - PREP_CNT) * 256 + tid;
        float4 v = ((const float4*)x_in)[i];
        f16x4 o;
        o[0] = (_Float16)v.x; o[1] = (_Float16)v.y;
        o[2] = (_Float16)v.z; o[3] = (_Float16)v.w;
        ((f16x4*)x16)[i] = o;
    } else {
        int tb = b - (PREP_CNT + PREP_CONV);
        int z  = tb >> 8;            // 0..3
        int rem = tb & 255;
        int bxi = rem & 15, byi = rem >> 4;
        if (z == 3 && bxi >= 2) return;   // W3 has only 64 cols
        const float* W = (z == 0) ? Wa : (z == 1) ? Wb : (z == 2) ? Wc : Wd;
        _Float16*    T = (z == 0) ? Ta : (z == 1) ? Tb : (z == 2) ? Tc : Td;
        const int ldW = (z == 3) ? 64 : 512;
        __shared__ float t[32][33];
        int bx = bxi * 32, by = byi * 32;
        int tx = tid & 31, ty = tid >> 5;   // 32 x 8
        #pragma unroll
        for (int i = 0; i < 32; i += 8)
            t[ty + i][tx] = W[(size_t)(by + ty + i) * ldW + bx + tx];
        __syncthreads();
        #pragma unroll
        for (int i = 0; i < 32; i += 8)
            T[(size_t)(bx + ty + i) * 512 + by + tx] = (_Float16)t[tx][ty + i];
    }
}

// ---------------------------------------------------------------------------
// Device-side exclusive scan of deg (tail block of the encoder GEMM launch)
// ---------------------------------------------------------------------------
__device__ void exscan_dev(const int* __restrict__ deg, int* __restrict__ off,
                           int* __restrict__ cursor, int* partial /* LDS[256] */)
{
    const int tid = threadIdx.x;
    const int chunk = (NNODES + 255) / 256; // 40
    int begin = tid * chunk;
    int end   = begin + chunk; if (end > NNODES) end = NNODES;
    if (begin > NNODES) begin = NNODES;
    int s = 0;
    for (int i = begin; i < end; ++i) s += deg[i];
    partial[tid] = s;
    __syncthreads();
    for (int o = 1; o < 256; o <<= 1) {
        int v = (tid >= o) ? partial[tid - o] : 0;
        __syncthreads();
        partial[tid] += v;
        __syncthreads();
    }
    int run = (tid > 0) ? partial[tid - 1] : 0;  // exclusive prefix
    for (int i = begin; i < end; ++i) {
        off[i] = run; cursor[i] = run; run += deg[i];
    }
    if (tid == 255) off[NNODES] = run; // == EPLUS
}

// ---------------------------------------------------------------------------
// fp16 MFMA GEMM: C[M,N] = A16[M,K] @ Bt16[N,K]^T (+bias), 128x64 tile.
// Optional fused per-head attention scores (64-col tile == one head).
// tail==1: exscan (1 extra block); tail==2: CSR scatter (665 extra blocks).
// ---------------------------------------------------------------------------
__global__ __launch_bounds__(256) void gemm_f16_mfma(
    const _Float16* __restrict__ A16, const _Float16* __restrict__ Bt16,
    const float* __restrict__ bias, _Float16* __restrict__ C16,
    float* __restrict__ ssrc, float* __restrict__ sdst,
    const float* __restrict__ a_s, const float* __restrict__ a_d,
    int Mt, int Nn, int K,
    int tail, const int* __restrict__ tp0, int* __restrict__ tp1,
    int* __restrict__ tp2)
{
    __shared__ _Float16 As[128 * 32] __attribute__((aligned(16)));
    __shared__ _Float16 Bs[64 * 32]  __attribute__((aligned(16)));
    __shared__ float sS[2][128];
    __shared__ float sD[2][128];
    const int tid  = threadIdx.x;
    const int ncols = Nn >> 6;
    const int nb    = ncols * (Mt >> 7);
    const int bid   = blockIdx.x;

    if (bid >= nb) {   // tail work, overlapped with the GEMM blocks
        if (tail == 1) {
            exscan_dev(tp0, tp1, tp2, (int*)As);
        } else if (tail == 2) {
            int e = (bid - nb) * 256 + tid;
            if (e < EPLUS) {
                int srcN, dstN;
                if (e < EDGES) { srcN = tp0[e]; dstN = tp0[EDGES + e]; }
                else           { srcN = dstN = e - EDGES; }
                int pos = atomicAdd(&tp1[dstN], 1);
                tp2[pos] = srcN;
            }
        }
        return;
    }

    const int bt   = bid % ncols;        // col tile (== head when Nn==512)
    const int row0 = (bid / ncols) * 128;
    const int col0 = bt * 64;
    const int wave = tid >> 6;
    const int lane = tid & 63;
    const int wy = wave >> 1, wx = wave & 1;

    const int lrow = lane >> 2;
    const int lk   = (lane & 3) * 8;

    f32x4 acc[4][2] = {};

    for (int k0 = 0; k0 < K; k0 += 32) {
        if (k0) __syncthreads();
        #pragma unroll
        for (int r = 0; r < 2; ++r) {
            const int chunk = r * 4 + wave;
            const int trow  = chunk * 16 + lrow;
            GLD_LDS16(A16 + (size_t)(row0 + trow) * K + k0 + lk,
                      &As[chunk * 512]);
        }
        {
            const int trow = wave * 16 + lrow;
            GLD_LDS16(Bt16 + (size_t)(col0 + trow) * K + k0 + lk,
                      &Bs[wave * 512]);
        }
        __syncthreads();

        const int quad = lane >> 4;
        const int l16  = lane & 15;
        f16x8 af[4], bf[2];
        #pragma unroll
        for (int m = 0; m < 4; ++m)
            af[m] = *(const f16x8*)&As[(wy * 64 + m * 16 + l16) * 32 + quad * 8];
        #pragma unroll
        for (int n = 0; n < 2; ++n)
            bf[n] = *(const f16x8*)&Bs[(wx * 32 + n * 16 + l16) * 32 + quad * 8];
        #pragma unroll
        for (int m = 0; m < 4; ++m)
            #pragma unroll
            for (int n = 0; n < 2; ++n)
                acc[m][n] = __builtin_amdgcn_mfma_f32_16x16x32_f16(
                    af[m], bf[n], acc[m][n], 0, 0, 0);
    }

    const int quad = lane >> 4;
    const int l16  = lane & 15;
    #pragma unroll
    for (int m = 0; m < 4; ++m) {
        #pragma unroll
        for (int n = 0; n < 2; ++n) {
            const int col = col0 + wx * 32 + n * 16 + l16;
            const float bv = bias ? bias[col] : 0.0f;
            #pragma unroll
            for (int r = 0; r < 4; ++r) {
                const int row = row0 + wy * 64 + m * 16 + quad * 4 + r;
                C16[(size_t)row * Nn + col] = (_Float16)(acc[m][n][r] + bv);
            }
        }
    }

    if (ssrc) {   // fused per-head scores (bias-less layer GEMMs)
        float a_sv[2], a_dv[2];
        #pragma unroll
        for (int n = 0; n < 2; ++n) {
            const int col = col0 + wx * 32 + n * 16 + l16;
            a_sv[n] = a_s[col & 511];
            a_dv[n] = a_d[col & 511];
        }
        #pragma unroll
        for (int m = 0; m < 4; ++m) {
            #pragma unroll
            for (int r = 0; r < 4; ++r) {
                float vs = acc[m][0][r] * a_sv[0] + acc[m][1][r] * a_sv[1];
                float vd = acc[m][0][r] * a_dv[0] + acc[m][1][r] * a_dv[1];
                vs += __shfl_xor(vs, 1); vs += __shfl_xor(vs, 2);
                vs += __shfl_xor(vs, 4); vs += __shfl_xor(vs, 8);
                vd += __shfl_xor(vd, 1); vd += __shfl_xor(vd, 2);
                vd += __shfl_xor(vd, 4); vd += __shfl_xor(vd, 8);
                if (l16 == 0) {
                    const int lr = wy * 64 + m * 16 + quad * 4 + r;
                    sS[wx][lr] = vs;
                    sD[wx][lr] = vd;
                }
            }
        }
        __syncthreads();
        if (wx == 0 && l16 == 0) {
            const int head = bt;   // Nn==512: col tile == head
            #pragma unroll
            for (int m = 0; m < 4; ++m)
                #pragma unroll
                for (int r = 0; r < 4; ++r) {
                    const int lr = wy * 64 + m * 16 + quad * 4 + r;
                    const int row = row0 + lr;
                    ssrc[(size_t)row * HEADS8 + head] = sS[0][lr] + sS[1][lr];
                    sdst[(size_t)row * HEADS8 + head] = sD[0][lr] + sD[1][lr];
                }
        }
    }
}

// ---------------------------------------------------------------------------
// fp16 MFMA GEMM, N=64 (layer 3) with fused NH=1 scores. Padded rows.
// ---------------------------------------------------------------------------
__global__ __launch_bounds__(256) void gemm_f16_mfma_n64(
    const _Float16* __restrict__ A16, const _Float16* __restrict__ Bt16,
    _Float16* __restrict__ C16,
    float* __restrict__ ssrc, float* __restrict__ sdst,
    const float* __restrict__ a_s, const float* __restrict__ a_d)
{
    __shared__ _Float16 As[64 * 32] __attribute__((aligned(16)));
    __shared__ _Float16 Bs[64 * 32] __attribute__((aligned(16)));
    __shared__ float sS[2][64];
    __shared__ float sD[2][64];
    const int tid  = threadIdx.x;
    const int wave = tid >> 6;
    const int lane = tid & 63;
    const int row0 = blockIdx.x * 64;
    const int wy = wave >> 1, wx = wave & 1;

    const int lrow = lane >> 2;
    const int lk   = (lane & 3) * 8;

    f32x4 acc[2][2] = {};

    for (int k0 = 0; k0 < 512; k0 += 32) {
        if (k0) __syncthreads();
        {
            const int trow = wave * 16 + lrow;
            GLD_LDS16(A16 + (size_t)(row0 + trow) * 512 + k0 + lk, &As[wave * 512]);
            GLD_LDS16(Bt16 + (size_t)trow * 512 + k0 + lk, &Bs[wave * 512]);
        }
        __syncthreads();

        const int quad = lane >> 4;
        const int l16  = lane & 15;
        f16x8 af[2], bf[2];
        #pragma unroll
        for (int m = 0; m < 2; ++m)
            af[m] = *(const f16x8*)&As[(wy * 32 + m * 16 + l16) * 32 + quad * 8];
        #pragma unroll
        for (int n = 0; n < 2; ++n)
            bf[n] = *(const f16x8*)&Bs[(wx * 32 + n * 16 + l16) * 32 + quad * 8];
        #pragma unroll
        for (int m = 0; m < 2; ++m)
            #pragma unroll
            for (int n = 0; n < 2; ++n)
                acc[m][n] = __builtin_amdgcn_mfma_f32_16x16x32_f16(
                    af[m], bf[n], acc[m][n], 0, 0, 0);
    }

    const int quad = lane >> 4;
    const int l16  = lane & 15;
    #pragma unroll
    for (int m = 0; m < 2; ++m)
        #pragma unroll
        for (int n = 0; n < 2; ++n) {
            const int col = wx * 32 + n * 16 + l16;
            #pragma unroll
            for (int r = 0; r < 4; ++r) {
                const int row = row0 + wy * 32 + m * 16 + quad * 4 + r;
                C16[(size_t)row * 64 + col] = (_Float16)acc[m][n][r];
            }
        }

    // fused scores (heads=1)
    {
        float a_sv[2], a_dv[2];
        #pragma unroll
        for (int n = 0; n < 2; ++n) {
            const int col = wx * 32 + n * 16 + l16;
            a_sv[n] = a_s[col];
            a_dv[n] = a_d[col];
        }
        #pragma unroll
        for (int m = 0; m < 2; ++m)
            #pragma unroll
            for (int r = 0; r < 4; ++r) {
                float vs = acc[m][0][r] * a_sv[0] + acc[m][1][r] * a_sv[1];
                float vd = acc[m][0][r] * a_dv[0] + acc[m][1][r] * a_dv[1];
                vs += __shfl_xor(vs, 1); vs += __shfl_xor(vs, 2);
                vs += __shfl_xor(vs, 4); vs += __shfl_xor(vs, 8);
                vd += __shfl_xor(vd, 1); vd += __shfl_xor(vd, 2);
                vd += __shfl_xor(vd, 4); vd += __shfl_xor(vd, 8);
                if (l16 == 0) {
                    const int lr = wy * 32 + m * 16 + quad * 4 + r;
                    sS[wx][lr] = vs;
                    sD[wx][lr] = vd;
                }
            }
        __syncthreads();
        if (wx == 0 && l16 == 0) {
            #pragma unroll
            for (int m = 0; m < 2; ++m)
                #pragma unroll
                for (int r = 0; r < 4; ++r) {
                    const int lr = wy * 32 + m * 16 + quad * 4 + r;
                    const int row = row0 + lr;
                    ssrc[row] = sS[0][lr] + sS[1][lr];
                    sdst[row] = sD[0][lr] + sD[1][lr];
                }
        }
    }
}

// ---------------------------------------------------------------------------
// Segment-softmax aggregation, NH=8 fp16, single pass; f16 output.
// (round-2 proven version: 1 node per 64-thread block)
// ---------------------------------------------------------------------------
__global__ __launch_bounds__(64) void gat_aggregate8(
    const _Float16* __restrict__ Hf, const float* __restrict__ ssrc,
    const float* __restrict__ sdst, const int* __restrict__ off,
    const int* __restrict__ csr, const float* __restrict__ bias,
    _Float16* __restrict__ out)
{
    const int n    = blockIdx.x;
    const int lane = threadIdx.x;
    const int head = lane >> 3;
    const int e0 = off[n], e1 = off[n + 1];

    float4 sd0 = ((const float4*)(sdst + n * 8))[0];
    float4 sd1 = ((const float4*)(sdst + n * 8))[1];
    float sd[8] = {sd0.x, sd0.y, sd0.z, sd0.w, sd1.x, sd1.y, sd1.z, sd1.w};

    __shared__ float exL[64 * 8];
    __shared__ int   srcL[64];
    float acc[8]  = {};
    float ssum[8] = {};
    for (int base = e0; base < e1; base += 64) {
        int cnt = e1 - base; if (cnt > 64) cnt = 64;
        if (lane < cnt) {
            int s = csr[base + lane];
            srcL[lane] = s;
            float4 s0 = ((const float4*)(ssrc + s * 8))[0];
            float4 s1 = ((const float4*)(ssrc + s * 8))[1];
            float lv[8] = {s0.x, s0.y, s0.z, s0.w, s1.x, s1.y, s1.z, s1.w};
            #pragma unroll
            for (int h = 0; h < 8; ++h) {
                float l = lv[h] + sd[h];
                l = (l > 0.f) ? l : 0.2f * l;
                float ex = __expf(l);
                exL[lane * 8 + h] = ex;
                ssum[h] += ex;
            }
        }
        __syncthreads();
        int j = 0;
        for (; j + 4 <= cnt; j += 4) {
            const int s0 = srcL[j],     s1 = srcL[j + 1];
            const int s2 = srcL[j + 2], s3 = srcL[j + 3];
            f16x8 h0 = *(const f16x8*)(Hf + (size_t)s0 * HC + lane * 8);
            f16x8 h1 = *(const f16x8*)(Hf + (size_t)s1 * HC + lane * 8);
            f16x8 h2 = *(const f16x8*)(Hf + (size_t)s2 * HC + lane * 8);
            f16x8 h3 = *(const f16x8*)(Hf + (size_t)s3 * HC + lane * 8);
            const float a0 = exL[(j)     * 8 + head];
            const float a1 = exL[(j + 1) * 8 + head];
            const float a2 = exL[(j + 2) * 8 + head];
            const float a3 = exL[(j + 3) * 8 + head];
            #pragma unroll
            for (int c = 0; c < 8; ++c) {
                acc[c] = fmaf(a0, (float)h0[c], acc[c]);
                acc[c] = fmaf(a1, (float)h1[c], acc[c]);
                acc[c] = fmaf(a2, (float)h2[c], acc[c]);
                acc[c] = fmaf(a3, (float)h3[c], acc[c]);
            }
        }
        for (; j < cnt; ++j) {
            const int s = srcL[j];
            f16x8 hv = *(const f16x8*)(Hf + (size_t)s * HC + lane * 8);
            const float al = exL[j * 8 + head];
            #pragma unroll
            for (int c = 0; c < 8; ++c)
                acc[c] = fmaf(al, (float)hv[c], acc[c]);
        }
        __syncthreads();
    }
    #pragma unroll
    for (int h = 0; h < 8; ++h)
        #pragma unroll
        for (int o = 1; o < 64; o <<= 1)
            ssum[h] += __shfl_xor(ssum[h], o);

    const float inv = 1.0f / (ssum[head] + 1e-16f);
    const float* bp = bias + lane * 8;
    f16x8 ov;
    #pragma unroll
    for (int c = 0; c < 8; ++c)
        ov[c] = (_Float16)(acc[c] * inv + bp[c]);
    *(f16x8*)(out + (size_t)n * HC + lane * 8) = ov;
}

// NH=1 fp16 aggregate (layer 3), single pass, lane = channel; unrolled x4
__global__ __launch_bounds__(64) void gat_aggregate1(
    const _Float16* __restrict__ Hf, const float* __restrict__ ssrc,
    const float* __restrict__ sdst, const int* __restrict__ off,
    const int* __restrict__ csr, const float* __restrict__ bias,
    float* __restrict__ out)
{
    const int n    = blockIdx.x;
    const int lane = threadIdx.x;
    const int e0 = off[n], e1 = off[n + 1];
    const float sd = sdst[n];

    __shared__ float exL[64];
    __shared__ int   srcL[64];
    float acc = 0.f, ssum = 0.f;
    for (int base = e0; base < e1; base += 64) {
        int cnt = e1 - base; if (cnt > 64) cnt = 64;
        if (lane < cnt) {
            int s = csr[base + lane];
            srcL[lane] = s;
            float l = ssrc[s] + sd;
            l = (l > 0.f) ? l : 0.2f * l;
            float ex = __expf(l);
            exL[lane] = ex;
            ssum += ex;
        }
        __syncthreads();
        int j = 0;
        for (; j + 4 <= cnt; j += 4) {
            const int s0 = srcL[j],     s1 = srcL[j + 1];
            const int s2 = srcL[j + 2], s3 = srcL[j + 3];
            float h0 = (float)Hf[(size_t)s0 * 64 + lane];
            float h1 = (float)Hf[(size_t)s1 * 64 + lane];
            float h2 = (float)Hf[(size_t)s2 * 64 + lane];
            float h3 = (float)Hf[(size_t)s3 * 64 + lane];
            acc = fmaf(exL[j],     h0, acc);
            acc = fmaf(exL[j + 1], h1, acc);
            acc = fmaf(exL[j + 2], h2, acc);
            acc = fmaf(exL[j + 3], h3, acc);
        }
        for (; j < cnt; ++j)
            acc = fmaf(exL[j], (float)Hf[(size_t)srcL[j] * 64 + lane], acc);
        __syncthreads();
    }
    #pragma unroll
    for (int o = 1; o < 64; o <<= 1)
        ssum += __shfl_xor(ssum, o);

    out[(size_t)n * 64 + lane] = acc / (ssum + 1e-16f) + bias[lane];
}

// ---------------------------------------------------------------------------
// BatchNorm stats (f16): ZERO data atomics. 128 blocks compute partials,
// store them PLAIN in transposed layout psum[ch][NSTAT] (finalize-contiguous),
// release-fence, ticket; the last block acquire-fences and reduces 512KB of
// partials with vectorized plain loads. Atomic count: 128 (ticket only).
// ---------------------------------------------------------------------------
__global__ __launch_bounds__(256) void bn_stats_f16(
    const _Float16* __restrict__ x, int rows,
    float* __restrict__ psum, float* __restrict__ psq,   // [HC][NSTAT] each
    const float* __restrict__ g, const float* __restrict__ be,
    float* __restrict__ scale, float* __restrict__ shift,
    float invN, int* __restrict__ ticket)
{
    const int t    = threadIdx.x;
    const int lane = t & 63;
    const int wv   = t >> 6;
    const int w    = blockIdx.x * 4 + wv;     // wave id 0..511
    float s[8] = {}, q[8] = {};
    for (int r = w; r < rows; r += NSTAT * 4) {
        f16x8 v = *(const f16x8*)(x + (size_t)r * HC + lane * 8);
        #pragma unroll
        for (int j = 0; j < 8; ++j) {
            float f = (float)v[j];
            s[j] += f; q[j] += f * f;
        }
    }
    __shared__ float ls[4][HC];
    __shared__ float lq[4][HC];
    #pragma unroll
    for (int j = 0; j < 8; ++j) {
        ls[wv][lane * 8 + j] = s[j];
        lq[wv][lane * 8 + j] = q[j];
    }
    __syncthreads();
    // thread t owns channels t and t+256: plain stores of block partials
    {
        const int bid = blockIdx.x;
        #pragma unroll
        for (int k = 0; k < 2; ++k) {
            const int ch = t + k * 256;
            psum[ch * NSTAT + bid] = ls[0][ch] + ls[1][ch] + ls[2][ch] + ls[3][ch];
            psq [ch * NSTAT + bid] = lq[0][ch] + lq[1][ch] + lq[2][ch] + lq[3][ch];
        }
    }
    __threadfence();                       // release partials device-wide
    __shared__ int lastf;
    if (t == 0) lastf = (atomicAdd(ticket, 1) == NSTAT - 1) ? 1 : 0;
    __syncthreads();
    if (!lastf) return;
    __threadfence();                       // acquire others' partials

    #pragma unroll
    for (int k = 0; k < 2; ++k) {
        const int ch = t + k * 256;
        const float4* ps = (const float4*)&psum[ch * NSTAT];
        const float4* pq = (const float4*)&psq [ch * NSTAT];
        float S = 0.f, Q = 0.f;
        #pragma unroll
        for (int p = 0; p < NSTAT / 4; ++p) {
            float4 a = ps[p], b = pq[p];
            S += a.x + a.y + a.z + a.w;
            Q += b.x + b.y + b.z + b.w;
        }
        float mu  = S * invN;
        float var = Q * invN - mu * mu;
        float sc  = g[ch] / sqrtf(var + 1e-5f);
        scale[ch] = sc;
        shift[ch] = be[ch] - mu * sc;
    }
    if (t == 0) *ticket = 0;               // self-reset for graph replay
}

// fp32 stats (layer 3, cols=64): same zero-atomic structure, 64 blocks
__global__ __launch_bounds__(256) void bn_stats3(
    const float* __restrict__ x,
    float* __restrict__ psum, float* __restrict__ psq,   // [CH][NSTAT3] each
    const float* __restrict__ g, const float* __restrict__ be,
    float* __restrict__ scale, float* __restrict__ shift,
    float invN, int* __restrict__ ticket)
{
    const int t    = threadIdx.x;
    const int c4   = (t & 15) * 4;  // 4 cols; 16 threads cover a 256B row
    const int rsub = t >> 4;        // 0..15: 16 rows in flight per block
    float s[4] = {}, q[4] = {};
    for (int r = blockIdx.x * 16 + rsub; r < NNODES; r += NSTAT3 * 16) {
        float4 v = *(const float4*)(x + (size_t)r * CH + c4);
        s[0] += v.x; q[0] += v.x * v.x;
        s[1] += v.y; q[1] += v.y * v.y;
        s[2] += v.z; q[2] += v.z * v.z;
        s[3] += v.w; q[3] += v.w * v.w;
    }
    __shared__ float ls[16][CH];
    __shared__ float lq[16][CH];
    #pragma unroll
    for (int j = 0; j < 4; ++j) {
        ls[rsub][c4 + j] = s[j];
        lq[rsub][c4 + j] = q[j];
    }
    __syncthreads();
    if (t < CH) {
        float tot = 0.f;
        #pragma unroll
        for (int p = 0; p < 16; ++p) tot += ls[p][t];
        psum[t * NSTAT3 + blockIdx.x] = tot;
    } else if (t < 2 * CH) {
        const int ch = t - CH;
        float tot = 0.f;
        #pragma unroll
        for (int p = 0; p < 16; ++p) tot += lq[p][ch];
        psq[ch * NSTAT3 + blockIdx.x] = tot;
    }
    __threadfence();
    __shared__ int lastf;
    if (t == 0) lastf = (atomicAdd(ticket, 1) == NSTAT3 - 1) ? 1 : 0;
    __syncthreads();
    if (!lastf) return;
    __threadfence();

    if (t < CH) {
        const float4* ps = (const float4*)&psum[t * NSTAT3];
        const float4* pq = (const float4*)&psq [t * NSTAT3];
        float S = 0.f, Q = 0.f;
        #pragma unroll
        for (int p = 0; p < NSTAT3 / 4; ++p) {
            float4 a = ps[p], b = pq[p];
            S += a.x + a.y + a.z + a.w;
            Q += b.x + b.y + b.z + b.w;
        }
        float mu  = S * invN;
        float var = Q * invN - mu * mu;
        float sc  = g[t] / sqrtf(var + 1e-5f);
        scale[t] = sc;
        shift[t] = be[t] - mu * sc;
    }
    if (t == 0) *ticket = 0;
}

// f16 in, f16 residual, f16 out: v = elu(x*scale + shift) + res  (16B/lane)
__global__ void bn_apply16(const _Float16* __restrict__ xin,
                           const _Float16* __restrict__ res,
                           const float* __restrict__ scale,
                           const float* __restrict__ shift,
                           _Float16* __restrict__ out, size_t total8)
{
    size_t i = (size_t)blockIdx.x * blockDim.x + threadIdx.x;
    if (i >= total8) return;
    int c = (int)((i * 8) & (size_t)(HC - 1));
    f16x8 xv = ((const f16x8*)xin)[i];
    f16x8 rv = ((const f16x8*)res)[i];
    float4 sa = *(const float4*)(scale + c);
    float4 sb = *(const float4*)(scale + c + 4);
    float4 ha = *(const float4*)(shift + c);
    float4 hb = *(const float4*)(shift + c + 4);
    float sc[8] = {sa.x, sa.y, sa.z, sa.w, sb.x, sb.y, sb.z, sb.w};
    float sh[8] = {ha.x, ha.y, ha.z, ha.w, hb.x, hb.y, hb.z, hb.w};
    f16x8 o;
    #pragma unroll
    for (int j = 0; j < 8; ++j) {
        float v = (float)xv[j] * sc[j] + sh[j];
        v = (v > 0.f) ? v : expm1f(v);
        o[j] = (_Float16)(v + (float)rv[j]);
    }
    ((f16x8*)out)[i] = o;
}

// ---------------------------------------------------------------------------
// Fused global-mean-pool + BN3 affine (affine commutes with mean) + linear
// ---------------------------------------------------------------------------
__global__ __launch_bounds__(256) void pool_linear(
    const float* __restrict__ x, const int* __restrict__ goff,
    const float* __restrict__ W, const float* __restrict__ b,
    const float* __restrict__ scale, const float* __restrict__ shift,
    float* __restrict__ out)
{
    const int g    = blockIdx.x;
    const int lane = threadIdx.x & 63;   // channel
    const int wave = threadIdx.x >> 6;   // 0..3
    const int r0 = goff[g], r1 = goff[g + 1];
    float s = 0.f;
    for (int r = r0 + wave; r < r1; r += 4)
        s += x[(size_t)r * CH + lane];
    __shared__ float red[4][CH];
    __shared__ float mean_l[CH];
    red[wave][lane] = s;
    __syncthreads();
    if (wave == 0) {
        float tot = red[0][lane] + red[1][lane] + red[2][lane] + red[3][lane];
        float cnt = (float)(r1 - r0);
        float m = tot / fmaxf(cnt, 1.0f);
        mean_l[lane] = m * scale[lane] + shift[lane];   // BN3 applied on mean
    }
    __syncthreads();
    if (threadIdx.x < NCLS) {
        const int j = threadIdx.x;
        float acc = b[j];
        for (int c = 0; c < CH; ++c)
            acc = fmaf(mean_l[c], W[c * NCLS + j], acc);
        out[g * NCLS + j] = acc;
    }
}

// ---------------------------------------------------------------------------
// Host launcher
// ---------------------------------------------------------------------------
extern "C" void kernel_launch(void* const* d_in, const int* in_sizes, int n_in,
                              void* d_out, int out_size, void* d_ws, size_t ws_size,
                              hipStream_t stream)
{
    const float* x_in  = (const float*)d_in[0];
    const int*   ei    = (const int*)  d_in[1];
    const int*   batch = (const int*)  d_in[2];
    const float* enc_W = (const float*)d_in[3];
    const float* enc_b = (const float*)d_in[4];
    const float* W1  = (const float*)d_in[5];
    const float* as1 = (const float*)d_in[6];
    const float* ad1 = (const float*)d_in[7];
    const float* b1  = (const float*)d_in[8];
    const float* g1  = (const float*)d_in[9];
    const float* be1 = (const float*)d_in[10];
    const float* W2  = (const float*)d_in[11];
    const float* as2 = (const float*)d_in[12];
    const float* ad2 = (const float*)d_in[13];
    const float* b2  = (const float*)d_in[14];
    const float* g2  = (const float*)d_in[15];
    const float* be2 = (const float*)d_in[16];
    const float* W3  = (const float*)d_in[17];
    const float* as3 = (const float*)d_in[18];
    const float* ad3 = (const float*)d_in[19];
    const float* b3  = (const float*)d_in[20];
    const float* g3  = (const float*)d_in[21];
    const float* be3 = (const float*)d_in[22];
    const float* linW = (const float*)d_in[23];
    const float* linb = (const float*)d_in[24];
    float* out = (float*)d_out;

    char* ws = (char*)d_ws;
    size_t off_b = 0;
    auto alloc = [&](size_t bytes) -> void* {
        void* p = ws + off_b;
        off_b = (off_b + bytes + 255) & ~(size_t)255;
        return p;
    };
    _Float16* f16A   = (_Float16*)alloc((size_t)MPAD * HC * 2);   // act buf A
    _Float16* f16B   = (_Float16*)alloc((size_t)MPAD * HC * 2);   // act buf B
    _Float16* H16    = (_Float16*)alloc((size_t)MPAD * HC * 2);   // GAT features
    _Float16* g16    = (_Float16*)alloc((size_t)NNODES * HC * 2); // aggregate out
    _Float16* h3_16  = (_Float16*)alloc((size_t)MPAD * CH * 2);
    float*    g3o    = (float*)alloc((size_t)NNODES * CH * 4);
    _Float16* encWt  = (_Float16*)alloc((size_t)HC * FIN * 2);
    _Float16* W1t    = (_Float16*)alloc((size_t)HC * HC * 2);
    _Float16* W2t    = (_Float16*)alloc((size_t)HC * HC * 2);
    _Float16* W3t    = (_Float16*)alloc((size_t)CH * HC * 2);
    float* ssrc   = (float*)alloc((size_t)MPAD * HEADS8 * 4);
    float* sdst   = (float*)alloc((size_t)MPAD * HEADS8 * 4);
    int*   deg    = (int*)  alloc((size_t)NNODES * 4);
    int*   offp   = (int*)  alloc((size_t)(NNODES + 1) * 4);
    int*   cursor = (int*)  alloc((size_t)NNODES * 4);
    int*   csr    = (int*)  alloc((size_t)EPLUS * 4);
    int*   goff   = (int*)  alloc((size_t)(NG + 1) * 4);
    float* psum   = (float*)alloc((size_t)HC * NSTAT * 4);   // 256 KB
    float* psq    = (float*)alloc((size_t)HC * NSTAT * 4);
    float* psum3  = (float*)alloc((size_t)CH * NSTAT3 * 4);  // 16 KB
    float* psq3   = (float*)alloc((size_t)CH * NSTAT3 * 4);
    float* bnsc   = (float*)alloc(HC * 4);
    float* bnsh   = (float*)alloc(HC * 4);
    int*   tickets= (int*)  alloc(4 * 4);

    // ---- Prep: histogram+goff, x fp16 convert, weight transposes (1 kernel)
    hipMemsetAsync(deg, 0, (size_t)NNODES * 4, stream);
    prep_all<<<PREP_CNT + PREP_CONV + 1024, 256, 0, stream>>>(
        ei, deg, batch, goff, x_in, f16A, enc_W, W1, W2, W3,
        encWt, W1t, W2t, W3t, tickets);

    const int NB = (HC / 64) * (MPAD / 128);         // 632 GEMM blocks
    const int SCAT = (EPLUS + 255) / 256;            // 665 scatter blocks

    // ---- Encoder GEMM; tail block runs the degree exclusive-scan
    gemm_f16_mfma<<<NB + 1, 256, 0, stream>>>(
        f16A, encWt, enc_b, f16B, nullptr, nullptr, nullptr, nullptr,
        MPAD, HC, FIN, 1, deg, offp, cursor);

    const size_t total8 = (size_t)NNODES * HC / 8;
    const int apply_blocks = (int)((total8 + 255) / 256);
    const float invN = 1.0f / NNODES;

    // ---- Layer 1: GEMM (+fused scores) with CSR scatter in tail blocks
    gemm_f16_mfma<<<NB + SCAT, 256, 0, stream>>>(
        f16B, W1t, nullptr, H16, ssrc, sdst, as1, ad1,
        MPAD, HC, HC, 2, ei, cursor, csr);
    gat_aggregate8<<<NNODES, 64, 0, stream>>>(H16, ssrc, sdst, offp, csr,
                                              b1, g16);
    bn_stats_f16<<<NSTAT, 256, 0, stream>>>(g16, NNODES, psum, psq,
                                            g1, be1, bnsc, bnsh, invN,
                                            tickets + 0);
    bn_apply16<<<apply_blocks, 256, 0, stream>>>(g16, f16B, bnsc, bnsh,
                                                 f16A, total8);

    // ---- Layer 2
    gemm_f16_mfma<<<NB, 256, 0, stream>>>(
        f16A, W2t, nullptr, H16, ssrc, sdst, as2, ad2,
        MPAD, HC, HC, 0, nullptr, nullptr, nullptr);
    gat_aggregate8<<<NNODES, 64, 0, stream>>>(H16, ssrc, sdst, offp, csr,
                                              b2, g16);
    bn_stats_f16<<<NSTAT, 256, 0, stream>>>(g16, NNODES, psum, psq,
                                            g2, be2, bnsc, bnsh, invN,
                                            tickets + 1);
    bn_apply16<<<apply_blocks, 256, 0, stream>>>(g16, f16A, bnsc, bnsh,
                                                 f16B, total8);

    // ---- Layer 3 (heads=1, C=64)
    gemm_f16_mfma_n64<<<MPAD / 64, 256, 0, stream>>>(f16B, W3t, h3_16,
                                                     ssrc, sdst, as3, ad3);
    gat_aggregate1<<<NNODES, 64, 0, stream>>>(h3_16, ssrc, sdst, offp, csr,
                                              b3, g3o);
    bn_stats3<<<NSTAT3, 256, 0, stream>>>(g3o, psum3, psq3, g3, be3,
                                          bnsc, bnsh, invN, tickets + 2);

    // ---- Fused pool + BN3 affine + final linear
    pool_linear<<<NG, 256, 0, stream>>>(g3o, goff, linW, linb, bnsc, bnsh,
                                        out);
}

// Round 6
// 323.844 us; speedup vs baseline: 2.8339x; 1.2602x over previous
//
#include <hip/hip_runtime.h>
#include <hip/hip_bf16.h>
#include <math.h>

// Problem constants (from reference)
#define NNODES 10000
#define RPAD   10240    // stats row padding (zero rows 10000..10239)
#define MPAD   10112    // 79 * 128 (GEMM row padding)
#define EDGES  160000
#define EPLUS  170000   // EDGES + NNODES self-loops
#define FIN    512
#define HEADS8 8
#define CH     64
#define HC     512      // HEADS8*CH
#define NG     64       // graphs
#define NCLS   64
#define NSTAT  256      // bn stats blocks (f16 path) -> 1024 waves
#define NSTAT3 64       // bn stats blocks (layer-3 fp32 path)

typedef _Float16 f16x8 __attribute__((ext_vector_type(8)));
typedef _Float16 f16x4 __attribute__((ext_vector_type(4)));
typedef _Float16 f16x2 __attribute__((ext_vector_type(2)));
typedef float    f32x4 __attribute__((ext_vector_type(4)));

#define GLD_LDS16(g, l)                                                        \
    __builtin_amdgcn_global_load_lds(                                          \
        (const __attribute__((address_space(1))) void*)(g),                    \
        (__attribute__((address_space(3))) void*)(l), 16, 0, 0)

// ---------------------------------------------------------------------------
// Fused prep: [0,665) dst-degree histogram + graph offsets + pad zeroing;
//             [665,5665) fp32->fp16 convert of x_in;
//             [5665,...) 4 weight transposes (fp32 KxN -> fp16 NxK)
// Blocks 0..59 zero g16 pad rows (240x512 f16); 60..74 zero g3o pad rows.
// ---------------------------------------------------------------------------
#define PREP_CNT  665
#define PREP_CONV 5000   // 10000*512/4 / 256
__global__ void prep_all(const int* __restrict__ ei, int* __restrict__ deg,
                         const int* __restrict__ batch, int* __restrict__ goff,
                         const float* __restrict__ x_in, _Float16* __restrict__ x16,
                         const float* __restrict__ Wa, const float* __restrict__ Wb,
                         const float* __restrict__ Wc, const float* __restrict__ Wd,
                         _Float16* __restrict__ Ta, _Float16* __restrict__ Tb,
                         _Float16* __restrict__ Tc, _Float16* __restrict__ Td,
                         _Float16* __restrict__ g16pad, float* __restrict__ g3opad)
{
    const int b   = blockIdx.x;
    const int tid = threadIdx.x;
    if (b < PREP_CNT) {
        const float4 z4 = make_float4(0.f, 0.f, 0.f, 0.f);
        if (b < 60)                       // 60*256 float4 = 240 rows x 512 f16
            ((float4*)g16pad)[b * 256 + tid] = z4;
        else if (b < 75)                  // 15*256 float4 = 240 rows x 64 f32
            ((float4*)g3opad)[(b - 60) * 256 + tid] = z4;
        int e = b * 256 + tid;
        if (e < NNODES) {
            int bb = batch[e];
            int bprev = (e == 0) ? -1 : batch[e - 1];
            for (int g = bprev + 1; g <= bb; ++g) goff[g] = e;
            if (e == NNODES - 1)
                for (int g = bb + 1; g <= NG; ++g) goff[g] = NNODES;
        }
        if (e >= EPLUS) return;
        int dst = (e < EDGES) ? ei[EDGES + e] : (e - EDGES);
        atomicAdd(&deg[dst], 1);
    } else if (b < PREP_CNT + PREP_CONV) {
        int i = (b - PREP_CNT) * 256 + tid;
        float4 v = ((const float4*)x_in)[i];
        f16x4 o;
        o[0] = (_Float16)v.x; o[1] = (_Float16)v.y;
        o[2] = (_Float16)v.z; o[3] = (_Float16)v.w;
        ((f16x4*)x16)[i] = o;
    } else {
        int tb = b - (PREP_CNT + PREP_CONV);
        int z  = tb >> 8;            // 0..3
        int rem = tb & 255;
        int bxi = rem & 15, byi = rem >> 4;
        if (z == 3 && bxi >= 2) return;   // W3 has only 64 cols
        const float* W = (z == 0) ? Wa : (z == 1) ? Wb : (z == 2) ? Wc : Wd;
        _Float16*    T = (z == 0) ? Ta : (z == 1) ? Tb : (z == 2) ? Tc : Td;
        const int ldW = (z == 3) ? 64 : 512;
        __shared__ float t[32][33];
        int bx = bxi * 32, by = byi * 32;
        int tx = tid & 31, ty = tid >> 5;   // 32 x 8
        #pragma unroll
        for (int i = 0; i < 32; i += 8)
            t[ty + i][tx] = W[(size_t)(by + ty + i) * ldW + bx + tx];
        __syncthreads();
        #pragma unroll
        for (int i = 0; i < 32; i += 8)
            T[(size_t)(bx + ty + i) * 512 + by + tx] = (_Float16)t[tx][ty + i];
    }
}

// ---------------------------------------------------------------------------
// Device-side exclusive scan of deg (tail block of the encoder GEMM launch)
// ---------------------------------------------------------------------------
__device__ void exscan_dev(const int* __restrict__ deg, int* __restrict__ off,
                           int* __restrict__ cursor, int* partial /* LDS[256] */)
{
    const int tid = threadIdx.x;
    const int chunk = (NNODES + 255) / 256; // 40
    int begin = tid * chunk;
    int end   = begin + chunk; if (end > NNODES) end = NNODES;
    if (begin > NNODES) begin = NNODES;
    int s = 0;
    for (int i = begin; i < end; ++i) s += deg[i];
    partial[tid] = s;
    __syncthreads();
    for (int o = 1; o < 256; o <<= 1) {
        int v = (tid >= o) ? partial[tid - o] : 0;
        __syncthreads();
        partial[tid] += v;
        __syncthreads();
    }
    int run = (tid > 0) ? partial[tid - 1] : 0;  // exclusive prefix
    for (int i = begin; i < end; ++i) {
        off[i] = run; cursor[i] = run; run += deg[i];
    }
    if (tid == 255) off[NNODES] = run; // == EPLUS
}

// ---------------------------------------------------------------------------
// fp16 MFMA GEMM: C[M,N] = A16[M,K] @ Bt16[N,K]^T (+bias), 128x64 tile.
// Optional fused per-head attention scores (64-col tile == one head).
// tail==1: exscan (1 extra block); tail==2: CSR scatter (665 extra blocks).
// ---------------------------------------------------------------------------
__global__ __launch_bounds__(256) void gemm_f16_mfma(
    const _Float16* __restrict__ A16, const _Float16* __restrict__ Bt16,
    const float* __restrict__ bias, _Float16* __restrict__ C16,
    float* __restrict__ ssrc, float* __restrict__ sdst,
    const float* __restrict__ a_s, const float* __restrict__ a_d,
    int Mt, int Nn, int K,
    int tail, const int* __restrict__ tp0, int* __restrict__ tp1,
    int* __restrict__ tp2)
{
    __shared__ _Float16 As[128 * 32] __attribute__((aligned(16)));
    __shared__ _Float16 Bs[64 * 32]  __attribute__((aligned(16)));
    __shared__ float sS[2][128];
    __shared__ float sD[2][128];
    const int tid  = threadIdx.x;
    const int ncols = Nn >> 6;
    const int nb    = ncols * (Mt >> 7);
    const int bid   = blockIdx.x;

    if (bid >= nb) {   // tail work, overlapped with the GEMM blocks
        if (tail == 1) {
            exscan_dev(tp0, tp1, tp2, (int*)As);
        } else if (tail == 2) {
            int e = (bid - nb) * 256 + tid;
            if (e < EPLUS) {
                int srcN, dstN;
                if (e < EDGES) { srcN = tp0[e]; dstN = tp0[EDGES + e]; }
                else           { srcN = dstN = e - EDGES; }
                int pos = atomicAdd(&tp1[dstN], 1);
                tp2[pos] = srcN;
            }
        }
        return;
    }

    const int bt   = bid % ncols;        // col tile (== head when Nn==512)
    const int row0 = (bid / ncols) * 128;
    const int col0 = bt * 64;
    const int wave = tid >> 6;
    const int lane = tid & 63;
    const int wy = wave >> 1, wx = wave & 1;

    const int lrow = lane >> 2;
    const int lk   = (lane & 3) * 8;

    f32x4 acc[4][2] = {};

    for (int k0 = 0; k0 < K; k0 += 32) {
        if (k0) __syncthreads();
        #pragma unroll
        for (int r = 0; r < 2; ++r) {
            const int chunk = r * 4 + wave;
            const int trow  = chunk * 16 + lrow;
            GLD_LDS16(A16 + (size_t)(row0 + trow) * K + k0 + lk,
                      &As[chunk * 512]);
        }
        {
            const int trow = wave * 16 + lrow;
            GLD_LDS16(Bt16 + (size_t)(col0 + trow) * K + k0 + lk,
                      &Bs[wave * 512]);
        }
        __syncthreads();

        const int quad = lane >> 4;
        const int l16  = lane & 15;
        f16x8 af[4], bf[2];
        #pragma unroll
        for (int m = 0; m < 4; ++m)
            af[m] = *(const f16x8*)&As[(wy * 64 + m * 16 + l16) * 32 + quad * 8];
        #pragma unroll
        for (int n = 0; n < 2; ++n)
            bf[n] = *(const f16x8*)&Bs[(wx * 32 + n * 16 + l16) * 32 + quad * 8];
        #pragma unroll
        for (int m = 0; m < 4; ++m)
            #pragma unroll
            for (int n = 0; n < 2; ++n)
                acc[m][n] = __builtin_amdgcn_mfma_f32_16x16x32_f16(
                    af[m], bf[n], acc[m][n], 0, 0, 0);
    }

    const int quad = lane >> 4;
    const int l16  = lane & 15;
    #pragma unroll
    for (int m = 0; m < 4; ++m) {
        #pragma unroll
        for (int n = 0; n < 2; ++n) {
            const int col = col0 + wx * 32 + n * 16 + l16;
            const float bv = bias ? bias[col] : 0.0f;
            #pragma unroll
            for (int r = 0; r < 4; ++r) {
                const int row = row0 + wy * 64 + m * 16 + quad * 4 + r;
                C16[(size_t)row * Nn + col] = (_Float16)(acc[m][n][r] + bv);
            }
        }
    }

    if (ssrc) {   // fused per-head scores (bias-less layer GEMMs)
        float a_sv[2], a_dv[2];
        #pragma unroll
        for (int n = 0; n < 2; ++n) {
            const int col = col0 + wx * 32 + n * 16 + l16;
            a_sv[n] = a_s[col & 511];
            a_dv[n] = a_d[col & 511];
        }
        #pragma unroll
        for (int m = 0; m < 4; ++m) {
            #pragma unroll
            for (int r = 0; r < 4; ++r) {
                float vs = acc[m][0][r] * a_sv[0] + acc[m][1][r] * a_sv[1];
                float vd = acc[m][0][r] * a_dv[0] + acc[m][1][r] * a_dv[1];
                vs += __shfl_xor(vs, 1); vs += __shfl_xor(vs, 2);
                vs += __shfl_xor(vs, 4); vs += __shfl_xor(vs, 8);
                vd += __shfl_xor(vd, 1); vd += __shfl_xor(vd, 2);
                vd += __shfl_xor(vd, 4); vd += __shfl_xor(vd, 8);
                if (l16 == 0) {
                    const int lr = wy * 64 + m * 16 + quad * 4 + r;
                    sS[wx][lr] = vs;
                    sD[wx][lr] = vd;
                }
            }
        }
        __syncthreads();
        if (wx == 0 && l16 == 0) {
            const int head = bt;   // Nn==512: col tile == head
            #pragma unroll
            for (int m = 0; m < 4; ++m)
                #pragma unroll
                for (int r = 0; r < 4; ++r) {
                    const int lr = wy * 64 + m * 16 + quad * 4 + r;
                    const int row = row0 + lr;
                    ssrc[(size_t)row * HEADS8 + head] = sS[0][lr] + sS[1][lr];
                    sdst[(size_t)row * HEADS8 + head] = sD[0][lr] + sD[1][lr];
                }
        }
    }
}

// ---------------------------------------------------------------------------
// fp16 MFMA GEMM, N=64 (layer 3) with fused NH=1 scores. Padded rows.
// ---------------------------------------------------------------------------
__global__ __launch_bounds__(256) void gemm_f16_mfma_n64(
    const _Float16* __restrict__ A16, const _Float16* __restrict__ Bt16,
    _Float16* __restrict__ C16,
    float* __restrict__ ssrc, float* __restrict__ sdst,
    const float* __restrict__ a_s, const float* __restrict__ a_d)
{
    __shared__ _Float16 As[64 * 32] __attribute__((aligned(16)));
    __shared__ _Float16 Bs[64 * 32] __attribute__((aligned(16)));
    __shared__ float sS[2][64];
    __shared__ float sD[2][64];
    const int tid  = threadIdx.x;
    const int wave = tid >> 6;
    const int lane = tid & 63;
    const int row0 = blockIdx.x * 64;
    const int wy = wave >> 1, wx = wave & 1;

    const int lrow = lane >> 2;
    const int lk   = (lane & 3) * 8;

    f32x4 acc[2][2] = {};

    for (int k0 = 0; k0 < 512; k0 += 32) {
        if (k0) __syncthreads();
        {
            const int trow = wave * 16 + lrow;
            GLD_LDS16(A16 + (size_t)(row0 + trow) * 512 + k0 + lk, &As[wave * 512]);
            GLD_LDS16(Bt16 + (size_t)trow * 512 + k0 + lk, &Bs[wave * 512]);
        }
        __syncthreads();

        const int quad = lane >> 4;
        const int l16  = lane & 15;
        f16x8 af[2], bf[2];
        #pragma unroll
        for (int m = 0; m < 2; ++m)
            af[m] = *(const f16x8*)&As[(wy * 32 + m * 16 + l16) * 32 + quad * 8];
        #pragma unroll
        for (int n = 0; n < 2; ++n)
            bf[n] = *(const f16x8*)&Bs[(wx * 32 + n * 16 + l16) * 32 + quad * 8];
        #pragma unroll
        for (int m = 0; m < 2; ++m)
            #pragma unroll
            for (int n = 0; n < 2; ++n)
                acc[m][n] = __builtin_amdgcn_mfma_f32_16x16x32_f16(
                    af[m], bf[n], acc[m][n], 0, 0, 0);
    }

    const int quad = lane >> 4;
    const int l16  = lane & 15;
    #pragma unroll
    for (int m = 0; m < 2; ++m)
        #pragma unroll
        for (int n = 0; n < 2; ++n) {
            const int col = wx * 32 + n * 16 + l16;
            #pragma unroll
            for (int r = 0; r < 4; ++r) {
                const int row = row0 + wy * 32 + m * 16 + quad * 4 + r;
                C16[(size_t)row * 64 + col] = (_Float16)acc[m][n][r];
            }
        }

    // fused scores (heads=1)
    {
        float a_sv[2], a_dv[2];
        #pragma unroll
        for (int n = 0; n < 2; ++n) {
            const int col = wx * 32 + n * 16 + l16;
            a_sv[n] = a_s[col];
            a_dv[n] = a_d[col];
        }
        #pragma unroll
        for (int m = 0; m < 2; ++m)
            #pragma unroll
            for (int r = 0; r < 4; ++r) {
                float vs = acc[m][0][r] * a_sv[0] + acc[m][1][r] * a_sv[1];
                float vd = acc[m][0][r] * a_dv[0] + acc[m][1][r] * a_dv[1];
                vs += __shfl_xor(vs, 1); vs += __shfl_xor(vs, 2);
                vs += __shfl_xor(vs, 4); vs += __shfl_xor(vs, 8);
                vd += __shfl_xor(vd, 1); vd += __shfl_xor(vd, 2);
                vd += __shfl_xor(vd, 4); vd += __shfl_xor(vd, 8);
                if (l16 == 0) {
                    const int lr = wy * 32 + m * 16 + quad * 4 + r;
                    sS[wx][lr] = vs;
                    sD[wx][lr] = vd;
                }
            }
        __syncthreads();
        if (wx == 0 && l16 == 0) {
            #pragma unroll
            for (int m = 0; m < 2; ++m)
                #pragma unroll
                for (int r = 0; r < 4; ++r) {
                    const int lr = wy * 32 + m * 16 + quad * 4 + r;
                    const int row = row0 + lr;
                    ssrc[row] = sS[0][lr] + sS[1][lr];
                    sdst[row] = sD[0][lr] + sD[1][lr];
                }
        }
    }
}

// ---------------------------------------------------------------------------
// Segment-softmax aggregation, NH=8 fp16, single pass; f16 output.
// (round-2 proven version: 1 node per 64-thread block)
// ---------------------------------------------------------------------------
__global__ __launch_bounds__(64) void gat_aggregate8(
    const _Float16* __restrict__ Hf, const float* __restrict__ ssrc,
    const float* __restrict__ sdst, const int* __restrict__ off,
    const int* __restrict__ csr, const float* __restrict__ bias,
    _Float16* __restrict__ out)
{
    const int n    = blockIdx.x;
    const int lane = threadIdx.x;
    const int head = lane >> 3;
    const int e0 = off[n], e1 = off[n + 1];

    float4 sd0 = ((const float4*)(sdst + n * 8))[0];
    float4 sd1 = ((const float4*)(sdst + n * 8))[1];
    float sd[8] = {sd0.x, sd0.y, sd0.z, sd0.w, sd1.x, sd1.y, sd1.z, sd1.w};

    __shared__ float exL[64 * 8];
    __shared__ int   srcL[64];
    float acc[8]  = {};
    float ssum[8] = {};
    for (int base = e0; base < e1; base += 64) {
        int cnt = e1 - base; if (cnt > 64) cnt = 64;
        if (lane < cnt) {
            int s = csr[base + lane];
            srcL[lane] = s;
            float4 s0 = ((const float4*)(ssrc + s * 8))[0];
            float4 s1 = ((const float4*)(ssrc + s * 8))[1];
            float lv[8] = {s0.x, s0.y, s0.z, s0.w, s1.x, s1.y, s1.z, s1.w};
            #pragma unroll
            for (int h = 0; h < 8; ++h) {
                float l = lv[h] + sd[h];
                l = (l > 0.f) ? l : 0.2f * l;
                float ex = __expf(l);
                exL[lane * 8 + h] = ex;
                ssum[h] += ex;
            }
        }
        __syncthreads();
        int j = 0;
        for (; j + 4 <= cnt; j += 4) {
            const int s0 = srcL[j],     s1 = srcL[j + 1];
            const int s2 = srcL[j + 2], s3 = srcL[j + 3];
            f16x8 h0 = *(const f16x8*)(Hf + (size_t)s0 * HC + lane * 8);
            f16x8 h1 = *(const f16x8*)(Hf + (size_t)s1 * HC + lane * 8);
            f16x8 h2 = *(const f16x8*)(Hf + (size_t)s2 * HC + lane * 8);
            f16x8 h3 = *(const f16x8*)(Hf + (size_t)s3 * HC + lane * 8);
            const float a0 = exL[(j)     * 8 + head];
            const float a1 = exL[(j + 1) * 8 + head];
            const float a2 = exL[(j + 2) * 8 + head];
            const float a3 = exL[(j + 3) * 8 + head];
            #pragma unroll
            for (int c = 0; c < 8; ++c) {
                acc[c] = fmaf(a0, (float)h0[c], acc[c]);
                acc[c] = fmaf(a1, (float)h1[c], acc[c]);
                acc[c] = fmaf(a2, (float)h2[c], acc[c]);
                acc[c] = fmaf(a3, (float)h3[c], acc[c]);
            }
        }
        for (; j < cnt; ++j) {
            const int s = srcL[j];
            f16x8 hv = *(const f16x8*)(Hf + (size_t)s * HC + lane * 8);
            const float al = exL[j * 8 + head];
            #pragma unroll
            for (int c = 0; c < 8; ++c)
                acc[c] = fmaf(al, (float)hv[c], acc[c]);
        }
        __syncthreads();
    }
    #pragma unroll
    for (int h = 0; h < 8; ++h)
        #pragma unroll
        for (int o = 1; o < 64; o <<= 1)
            ssum[h] += __shfl_xor(ssum[h], o);

    const float inv = 1.0f / (ssum[head] + 1e-16f);
    const float* bp = bias + lane * 8;
    f16x8 ov;
    #pragma unroll
    for (int c = 0; c < 8; ++c)
        ov[c] = (_Float16)(acc[c] * inv + bp[c]);
    *(f16x8*)(out + (size_t)n * HC + lane * 8) = ov;
}

// NH=1 fp16 aggregate (layer 3), single pass, lane = channel; unrolled x4
__global__ __launch_bounds__(64) void gat_aggregate1(
    const _Float16* __restrict__ Hf, const float* __restrict__ ssrc,
    const float* __restrict__ sdst, const int* __restrict__ off,
    const int* __restrict__ csr, const float* __restrict__ bias,
    float* __restrict__ out)
{
    const int n    = blockIdx.x;
    const int lane = threadIdx.x;
    const int e0 = off[n], e1 = off[n + 1];
    const float sd = sdst[n];

    __shared__ float exL[64];
    __shared__ int   srcL[64];
    float acc = 0.f, ssum = 0.f;
    for (int base = e0; base < e1; base += 64) {
        int cnt = e1 - base; if (cnt > 64) cnt = 64;
        if (lane < cnt) {
            int s = csr[base + lane];
            srcL[lane] = s;
            float l = ssrc[s] + sd;
            l = (l > 0.f) ? l : 0.2f * l;
            float ex = __expf(l);
            exL[lane] = ex;
            ssum += ex;
        }
        __syncthreads();
        int j = 0;
        for (; j + 4 <= cnt; j += 4) {
            const int s0 = srcL[j],     s1 = srcL[j + 1];
            const int s2 = srcL[j + 2], s3 = srcL[j + 3];
            float h0 = (float)Hf[(size_t)s0 * 64 + lane];
            float h1 = (float)Hf[(size_t)s1 * 64 + lane];
            float h2 = (float)Hf[(size_t)s2 * 64 + lane];
            float h3 = (float)Hf[(size_t)s3 * 64 + lane];
            acc = fmaf(exL[j],     h0, acc);
            acc = fmaf(exL[j + 1], h1, acc);
            acc = fmaf(exL[j + 2], h2, acc);
            acc = fmaf(exL[j + 3], h3, acc);
        }
        for (; j < cnt; ++j)
            acc = fmaf(exL[j], (float)Hf[(size_t)srcL[j] * 64 + lane], acc);
        __syncthreads();
    }
    #pragma unroll
    for (int o = 1; o < 64; o <<= 1)
        ssum += __shfl_xor(ssum, o);

    out[(size_t)n * 64 + lane] = acc / (ssum + 1e-16f) + bias[lane];
}

// ---------------------------------------------------------------------------
// BatchNorm stats (f16): partials ONLY (no fence/ticket/finalize).
// 256 blocks x 4 waves; each wave reads exactly 10 rows (RPAD=10240, zero-
// padded) as f16x8; fully unrolled -> 10 loads in flight. Block LDS reduce,
// coalesced plain stores psum[block][ch]. Kernel boundary = sync.
// ---------------------------------------------------------------------------
__global__ __launch_bounds__(256) void bn_stats_f16(
    const _Float16* __restrict__ x,
    float* __restrict__ psum, float* __restrict__ psq)   // [NSTAT][HC] each
{
    const int t    = threadIdx.x;
    const int lane = t & 63;
    const int wv   = t >> 6;
    const int w    = blockIdx.x * 4 + wv;     // wave id 0..1023
    float s[8] = {}, q[8] = {};
    #pragma unroll
    for (int k = 0; k < RPAD / 2048; ++k) {   // 5 iterations, 2 rows each
        const int r0 = w + k * 2048;
        f16x8 v0 = *(const f16x8*)(x + (size_t)r0 * HC + lane * 8);
        f16x8 v1 = *(const f16x8*)(x + (size_t)(r0 + 1024) * HC + lane * 8);
        #pragma unroll
        for (int j = 0; j < 8; ++j) {
            float f0 = (float)v0[j], f1 = (float)v1[j];
            s[j] += f0 + f1;
            q[j] += f0 * f0 + f1 * f1;
        }
    }
    __shared__ float ls[4][HC];
    __shared__ float lq[4][HC];
    #pragma unroll
    for (int j = 0; j < 8; ++j) {
        ls[wv][lane * 8 + j] = s[j];
        lq[wv][lane * 8 + j] = q[j];
    }
    __syncthreads();
    // coalesced partial stores: thread t owns channels t and t+256
    const size_t bo = (size_t)blockIdx.x * HC;
    #pragma unroll
    for (int k = 0; k < 2; ++k) {
        const int ch = t + k * 256;
        psum[bo + ch] = ls[0][ch] + ls[1][ch] + ls[2][ch] + ls[3][ch];
        psq [bo + ch] = lq[0][ch] + lq[1][ch] + lq[2][ch] + lq[3][ch];
    }
}

// fp32 stats (layer 3, cols=64): same structure, 64 blocks, RPAD rows
__global__ __launch_bounds__(256) void bn_stats3(
    const float* __restrict__ x,
    float* __restrict__ psum, float* __restrict__ psq)   // [NSTAT3][CH] each
{
    const int t    = threadIdx.x;
    const int c4   = (t & 15) * 4;  // 4 cols; 16 threads cover a 256B row
    const int rsub = t >> 4;        // 0..15: 16 rows in flight per block
    float s[4] = {}, q[4] = {};
    #pragma unroll
    for (int k = 0; k < RPAD / 1024; ++k) {   // 10 iterations
        const int r = blockIdx.x * 16 + rsub + k * 1024;
        float4 v = *(const float4*)(x + (size_t)r * CH + c4);
        s[0] += v.x; q[0] += v.x * v.x;
        s[1] += v.y; q[1] += v.y * v.y;
        s[2] += v.z; q[2] += v.z * v.z;
        s[3] += v.w; q[3] += v.w * v.w;
    }
    __shared__ float ls[16][CH];
    __shared__ float lq[16][CH];
    #pragma unroll
    for (int j = 0; j < 4; ++j) {
        ls[rsub][c4 + j] = s[j];
        lq[rsub][c4 + j] = q[j];
    }
    __syncthreads();
    if (t < CH) {
        float tot = 0.f;
        #pragma unroll
        for (int p = 0; p < 16; ++p) tot += ls[p][t];
        psum[(size_t)blockIdx.x * CH + t] = tot;
    } else if (t < 2 * CH) {
        const int ch = t - CH;
        float tot = 0.f;
        #pragma unroll
        for (int p = 0; p < 16; ++p) tot += lq[p][ch];
        psq[(size_t)blockIdx.x * CH + ch] = tot;
    }
}

// ---------------------------------------------------------------------------
// Generic BN finalize: grid = cols/16 blocks; 16 threads cooperate per
// channel (strided partial reads, LDS reduce). Kernel boundary is the sync.
// ---------------------------------------------------------------------------
__global__ __launch_bounds__(256) void bn_finalize(
    const float* __restrict__ psum, const float* __restrict__ psq,
    const float* __restrict__ g, const float* __restrict__ be,
    float* __restrict__ scale, float* __restrict__ shift,
    float invN, int cols, int np)
{
    const int t  = threadIdx.x;
    const int pg = t >> 4;            // 0..15 partial-group
    const int cl = t & 15;
    const int ch = blockIdx.x * 16 + cl;
    float S = 0.f, Q = 0.f;
    for (int p = pg; p < np; p += 16) {
        S += psum[(size_t)p * cols + ch];
        Q += psq [(size_t)p * cols + ch];
    }
    __shared__ float lsS[16][16];
    __shared__ float lsQ[16][16];
    lsS[pg][cl] = S;
    lsQ[pg][cl] = Q;
    __syncthreads();
    if (t < 16) {
        float S2 = 0.f, Q2 = 0.f;
        #pragma unroll
        for (int p = 0; p < 16; ++p) { S2 += lsS[p][t]; Q2 += lsQ[p][t]; }
        const int c = blockIdx.x * 16 + t;
        float mu  = S2 * invN;
        float var = Q2 * invN - mu * mu;
        float sc  = g[c] / sqrtf(var + 1e-5f);
        scale[c] = sc;
        shift[c] = be[c] - mu * sc;
    }
}

// f16 in, f16 residual, f16 out: v = elu(x*scale + shift) + res  (16B/lane)
__global__ void bn_apply16(const _Float16* __restrict__ xin,
                           const _Float16* __restrict__ res,
                           const float* __restrict__ scale,
                           const float* __restrict__ shift,
                           _Float16* __restrict__ out, size_t total8)
{
    size_t i = (size_t)blockIdx.x * blockDim.x + threadIdx.x;
    if (i >= total8) return;
    int c = (int)((i * 8) & (size_t)(HC - 1));
    f16x8 xv = ((const f16x8*)xin)[i];
    f16x8 rv = ((const f16x8*)res)[i];
    float4 sa = *(const float4*)(scale + c);
    float4 sb = *(const float4*)(scale + c + 4);
    float4 ha = *(const float4*)(shift + c);
    float4 hb = *(const float4*)(shift + c + 4);
    float sc[8] = {sa.x, sa.y, sa.z, sa.w, sb.x, sb.y, sb.z, sb.w};
    float sh[8] = {ha.x, ha.y, ha.z, ha.w, hb.x, hb.y, hb.z, hb.w};
    f16x8 o;
    #pragma unroll
    for (int j = 0; j < 8; ++j) {
        float v = (float)xv[j] * sc[j] + sh[j];
        v = (v > 0.f) ? v : expm1f(v);
        o[j] = (_Float16)(v + (float)rv[j]);
    }
    ((f16x8*)out)[i] = o;
}

// ---------------------------------------------------------------------------
// Fused global-mean-pool + BN3 affine (affine commutes with mean) + linear
// ---------------------------------------------------------------------------
__global__ __launch_bounds__(256) void pool_linear(
    const float* __restrict__ x, const int* __restrict__ goff,
    const float* __restrict__ W, const float* __restrict__ b,
    const float* __restrict__ scale, const float* __restrict__ shift,
    float* __restrict__ out)
{
    const int g    = blockIdx.x;
    const int lane = threadIdx.x & 63;   // channel
    const int wave = threadIdx.x >> 6;   // 0..3
    const int r0 = goff[g], r1 = goff[g + 1];
    float s = 0.f;
    for (int r = r0 + wave; r < r1; r += 4)
        s += x[(size_t)r * CH + lane];
    __shared__ float red[4][CH];
    __shared__ float mean_l[CH];
    red[wave][lane] = s;
    __syncthreads();
    if (wave == 0) {
        float tot = red[0][lane] + red[1][lane] + red[2][lane] + red[3][lane];
        float cnt = (float)(r1 - r0);
        float m = tot / fmaxf(cnt, 1.0f);
        mean_l[lane] = m * scale[lane] + shift[lane];   // BN3 applied on mean
    }
    __syncthreads();
    if (threadIdx.x < NCLS) {
        const int j = threadIdx.x;
        float acc = b[j];
        for (int c = 0; c < CH; ++c)
            acc = fmaf(mean_l[c], W[c * NCLS + j], acc);
        out[g * NCLS + j] = acc;
    }
}

// ---------------------------------------------------------------------------
// Host launcher
// ---------------------------------------------------------------------------
extern "C" void kernel_launch(void* const* d_in, const int* in_sizes, int n_in,
                              void* d_out, int out_size, void* d_ws, size_t ws_size,
                              hipStream_t stream)
{
    const float* x_in  = (const float*)d_in[0];
    const int*   ei    = (const int*)  d_in[1];
    const int*   batch = (const int*)  d_in[2];
    const float* enc_W = (const float*)d_in[3];
    const float* enc_b = (const float*)d_in[4];
    const float* W1  = (const float*)d_in[5];
    const float* as1 = (const float*)d_in[6];
    const float* ad1 = (const float*)d_in[7];
    const float* b1  = (const float*)d_in[8];
    const float* g1  = (const float*)d_in[9];
    const float* be1 = (const float*)d_in[10];
    const float* W2  = (const float*)d_in[11];
    const float* as2 = (const float*)d_in[12];
    const float* ad2 = (const float*)d_in[13];
    const float* b2  = (const float*)d_in[14];
    const float* g2  = (const float*)d_in[15];
    const float* be2 = (const float*)d_in[16];
    const float* W3  = (const float*)d_in[17];
    const float* as3 = (const float*)d_in[18];
    const float* ad3 = (const float*)d_in[19];
    const float* b3  = (const float*)d_in[20];
    const float* g3  = (const float*)d_in[21];
    const float* be3 = (const float*)d_in[22];
    const float* linW = (const float*)d_in[23];
    const float* linb = (const float*)d_in[24];
    float* out = (float*)d_out;

    char* ws = (char*)d_ws;
    size_t off_b = 0;
    auto alloc = [&](size_t bytes) -> void* {
        void* p = ws + off_b;
        off_b = (off_b + bytes + 255) & ~(size_t)255;
        return p;
    };
    _Float16* f16A   = (_Float16*)alloc((size_t)MPAD * HC * 2);   // act buf A
    _Float16* f16B   = (_Float16*)alloc((size_t)MPAD * HC * 2);   // act buf B
    _Float16* H16    = (_Float16*)alloc((size_t)MPAD * HC * 2);   // GAT features
    _Float16* g16    = (_Float16*)alloc((size_t)RPAD * HC * 2);   // aggregate out (padded)
    _Float16* h3_16  = (_Float16*)alloc((size_t)MPAD * CH * 2);
    float*    g3o    = (float*)alloc((size_t)RPAD * CH * 4);      // padded
    _Float16* encWt  = (_Float16*)alloc((size_t)HC * FIN * 2);
    _Float16* W1t    = (_Float16*)alloc((size_t)HC * HC * 2);
    _Float16* W2t    = (_Float16*)alloc((size_t)HC * HC * 2);
    _Float16* W3t    = (_Float16*)alloc((size_t)CH * HC * 2);
    float* ssrc   = (float*)alloc((size_t)MPAD * HEADS8 * 4);
    float* sdst   = (float*)alloc((size_t)MPAD * HEADS8 * 4);
    int*   deg    = (int*)  alloc((size_t)NNODES * 4);
    int*   offp   = (int*)  alloc((size_t)(NNODES + 1) * 4);
    int*   cursor = (int*)  alloc((size_t)NNODES * 4);
    int*   csr    = (int*)  alloc((size_t)EPLUS * 4);
    int*   goff   = (int*)  alloc((size_t)(NG + 1) * 4);
    float* psum   = (float*)alloc((size_t)NSTAT * HC * 4);   // 512 KB
    float* psq    = (float*)alloc((size_t)NSTAT * HC * 4);
    float* psum3  = (float*)alloc((size_t)NSTAT3 * CH * 4);  // 16 KB
    float* psq3   = (float*)alloc((size_t)NSTAT3 * CH * 4);
    float* bnsc   = (float*)alloc(HC * 4);
    float* bnsh   = (float*)alloc(HC * 4);

    // ---- Prep: histogram+goff+pad-zeroing, x fp16 convert, weight transposes
    hipMemsetAsync(deg, 0, (size_t)NNODES * 4, stream);
    prep_all<<<PREP_CNT + PREP_CONV + 1024, 256, 0, stream>>>(
        ei, deg, batch, goff, x_in, f16A, enc_W, W1, W2, W3,
        encWt, W1t, W2t, W3t,
        g16 + (size_t)NNODES * HC, g3o + (size_t)NNODES * CH);

    const int NB = (HC / 64) * (MPAD / 128);         // 632 GEMM blocks
    const int SCAT = (EPLUS + 255) / 256;            // 665 scatter blocks

    // ---- Encoder GEMM; tail block runs the degree exclusive-scan
    gemm_f16_mfma<<<NB + 1, 256, 0, stream>>>(
        f16A, encWt, enc_b, f16B, nullptr, nullptr, nullptr, nullptr,
        MPAD, HC, FIN, 1, deg, offp, cursor);

    const size_t total8 = (size_t)NNODES * HC / 8;
    const int apply_blocks = (int)((total8 + 255) / 256);
    const float invN = 1.0f / NNODES;

    // ---- Layer 1: GEMM (+fused scores) with CSR scatter in tail blocks
    gemm_f16_mfma<<<NB + SCAT, 256, 0, stream>>>(
        f16B, W1t, nullptr, H16, ssrc, sdst, as1, ad1,
        MPAD, HC, HC, 2, ei, cursor, csr);
    gat_aggregate8<<<NNODES, 64, 0, stream>>>(H16, ssrc, sdst, offp, csr,
                                              b1, g16);
    bn_stats_f16<<<NSTAT, 256, 0, stream>>>(g16, psum, psq);
    bn_finalize<<<HC / 16, 256, 0, stream>>>(psum, psq, g1, be1, bnsc, bnsh,
                                             invN, HC, NSTAT);
    bn_apply16<<<apply_blocks, 256, 0, stream>>>(g16, f16B, bnsc, bnsh,
                                                 f16A, total8);

    // ---- Layer 2
    gemm_f16_mfma<<<NB, 256, 0, stream>>>(
        f16A, W2t, nullptr, H16, ssrc, sdst, as2, ad2,
        MPAD, HC, HC, 0, nullptr, nullptr, nullptr);
    gat_aggregate8<<<NNODES, 64, 0, stream>>>(H16, ssrc, sdst, offp, csr,
                                              b2, g16);
    bn_stats_f16<<<NSTAT, 256, 0, stream>>>(g16, psum, psq);
    bn_finalize<<<HC / 16, 256, 0, stream>>>(psum, psq, g2, be2, bnsc, bnsh,
                                             invN, HC, NSTAT);
    bn_apply16<<<apply_blocks, 256, 0, stream>>>(g16, f16A, bnsc, bnsh,
                                                 f16B, total8);

    // ---- Layer 3 (heads=1, C=64)
    gemm_f16_mfma_n64<<<MPAD / 64, 256, 0, stream>>>(f16B, W3t, h3_16,
                                                     ssrc, sdst, as3, ad3);
    gat_aggregate1<<<NNODES, 64, 0, stream>>>(h3_16, ssrc, sdst, offp, csr,
                                              b3, g3o);
    bn_stats3<<<NSTAT3, 256, 0, stream>>>(g3o, psum3, psq3);
    bn_finalize<<<CH / 16, 256, 0, stream>>>(psum3, psq3, g3, be3, bnsc, bnsh,
                                             invN, CH, NSTAT3);

    // ---- Fused pool + BN3 affine + final linear
    pool_linear<<<NG, 256, 0, stream>>>(g3o, goff, linW, linb, bnsc, bnsh,
                                        out);
}

// Round 7
// 313.453 us; speedup vs baseline: 2.9279x; 1.0331x over previous
//
#include <hip/hip_runtime.h>
#include <hip/hip_bf16.h>
#include <math.h>

// Problem constants (from reference)
#define NNODES 10000
#define RPAD   10240    // stats row padding (zero rows 10000..10239)
#define MPAD   10112    // 79 * 128 (GEMM row padding)
#define EDGES  160000
#define EPLUS  170000   // EDGES + NNODES self-loops
#define FIN    512
#define HEADS8 8
#define CH     64
#define HC     512      // HEADS8*CH
#define NG     64       // graphs
#define NCLS   64
#define NSTAT  256      // bn stats blocks (f16 path) -> 1024 waves
#define NSTAT3 64       // bn stats blocks (layer-3 fp32 path)

typedef _Float16 f16x8 __attribute__((ext_vector_type(8)));
typedef _Float16 f16x4 __attribute__((ext_vector_type(4)));
typedef _Float16 f16x2 __attribute__((ext_vector_type(2)));
typedef float    f32x4 __attribute__((ext_vector_type(4)));

#define GLD_LDS16(g, l)                                                        \
    __builtin_amdgcn_global_load_lds(                                          \
        (const __attribute__((address_space(1))) void*)(g),                    \
        (__attribute__((address_space(3))) void*)(l), 16, 0, 0)

// ---------------------------------------------------------------------------
// Fused prep: [0,665) dst-degree histogram + graph offsets + pad zeroing;
//             [665,5665) fp32->fp16 convert of x_in;
//             [5665,...) 4 weight transposes (fp32 KxN -> fp16 NxK)
// ---------------------------------------------------------------------------
#define PREP_CNT  665
#define PREP_CONV 5000   // 10000*512/4 / 256
__global__ void prep_all(const int* __restrict__ ei, int* __restrict__ deg,
                         const int* __restrict__ batch, int* __restrict__ goff,
                         const float* __restrict__ x_in, _Float16* __restrict__ x16,
                         const float* __restrict__ Wa, const float* __restrict__ Wb,
                         const float* __restrict__ Wc, const float* __restrict__ Wd,
                         _Float16* __restrict__ Ta, _Float16* __restrict__ Tb,
                         _Float16* __restrict__ Tc, _Float16* __restrict__ Td,
                         _Float16* __restrict__ g16pad, float* __restrict__ g3opad)
{
    const int b   = blockIdx.x;
    const int tid = threadIdx.x;
    if (b < PREP_CNT) {
        const float4 z4 = make_float4(0.f, 0.f, 0.f, 0.f);
        if (b < 60)                       // 60*256 float4 = 240 rows x 512 f16
            ((float4*)g16pad)[b * 256 + tid] = z4;
        else if (b < 75)                  // 15*256 float4 = 240 rows x 64 f32
            ((float4*)g3opad)[(b - 60) * 256 + tid] = z4;
        int e = b * 256 + tid;
        if (e < NNODES) {
            int bb = batch[e];
            int bprev = (e == 0) ? -1 : batch[e - 1];
            for (int g = bprev + 1; g <= bb; ++g) goff[g] = e;
            if (e == NNODES - 1)
                for (int g = bb + 1; g <= NG; ++g) goff[g] = NNODES;
        }
        if (e >= EPLUS) return;
        int dst = (e < EDGES) ? ei[EDGES + e] : (e - EDGES);
        atomicAdd(&deg[dst], 1);
    } else if (b < PREP_CNT + PREP_CONV) {
        int i = (b - PREP_CNT) * 256 + tid;
        float4 v = ((const float4*)x_in)[i];
        f16x4 o;
        o[0] = (_Float16)v.x; o[1] = (_Float16)v.y;
        o[2] = (_Float16)v.z; o[3] = (_Float16)v.w;
        ((f16x4*)x16)[i] = o;
    } else {
        int tb = b - (PREP_CNT + PREP_CONV);
        int z  = tb >> 8;            // 0..3
        int rem = tb & 255;
        int bxi = rem & 15, byi = rem >> 4;
        if (z == 3 && bxi >= 2) return;   // W3 has only 64 cols
        const float* W = (z == 0) ? Wa : (z == 1) ? Wb : (z == 2) ? Wc : Wd;
        _Float16*    T = (z == 0) ? Ta : (z == 1) ? Tb : (z == 2) ? Tc : Td;
        const int ldW = (z == 3) ? 64 : 512;
        __shared__ float t[32][33];
        int bx = bxi * 32, by = byi * 32;
        int tx = tid & 31, ty = tid >> 5;   // 32 x 8
        #pragma unroll
        for (int i = 0; i < 32; i += 8)
            t[ty + i][tx] = W[(size_t)(by + ty + i) * ldW + bx + tx];
        __syncthreads();
        #pragma unroll
        for (int i = 0; i < 32; i += 8)
            T[(size_t)(bx + ty + i) * 512 + by + tx] = (_Float16)t[tx][ty + i];
    }
}

// ---------------------------------------------------------------------------
// Device-side exclusive scan of deg (tail block of the encoder GEMM launch)
// ---------------------------------------------------------------------------
__device__ void exscan_dev(const int* __restrict__ deg, int* __restrict__ off,
                           int* __restrict__ cursor, int* partial /* LDS[256] */)
{
    const int tid = threadIdx.x;
    const int chunk = (NNODES + 255) / 256; // 40
    int begin = tid * chunk;
    int end   = begin + chunk; if (end > NNODES) end = NNODES;
    if (begin > NNODES) begin = NNODES;
    int s = 0;
    for (int i = begin; i < end; ++i) s += deg[i];
    partial[tid] = s;
    __syncthreads();
    for (int o = 1; o < 256; o <<= 1) {
        int v = (tid >= o) ? partial[tid - o] : 0;
        __syncthreads();
        partial[tid] += v;
        __syncthreads();
    }
    int run = (tid > 0) ? partial[tid - 1] : 0;  // exclusive prefix
    for (int i = begin; i < end; ++i) {
        off[i] = run; cursor[i] = run; run += deg[i];
    }
    if (tid == 255) off[NNODES] = run; // == EPLUS
}

// ---------------------------------------------------------------------------
// fp16 MFMA GEMM: C[M,N] = A16[M,K] @ Bt16[N,K]^T (+bias), 128x128 tile.
// 2x2 waves, each wave owns a 64x64 sub-tile (4x4 fragments, 16 MFMA/K-step).
// With 64-col heads a wave's columns == ONE head -> fused scores reduce
// entirely in-wave and write ssrc/sdst directly (no LDS, no extra barrier).
// tail==1: exscan (1 extra block); tail==2: CSR scatter (665 extra blocks).
// ---------------------------------------------------------------------------
__global__ __launch_bounds__(256) void gemm_f16_mfma(
    const _Float16* __restrict__ A16, const _Float16* __restrict__ Bt16,
    const float* __restrict__ bias, _Float16* __restrict__ C16,
    float* __restrict__ ssrc, float* __restrict__ sdst,
    const float* __restrict__ a_s, const float* __restrict__ a_d,
    int Mt, int Nn, int K,
    int tail, const int* __restrict__ tp0, int* __restrict__ tp1,
    int* __restrict__ tp2)
{
    __shared__ _Float16 As[128 * 32] __attribute__((aligned(16)));
    __shared__ _Float16 Bs[128 * 32] __attribute__((aligned(16)));
    const int tid  = threadIdx.x;
    const int ncols = Nn >> 7;           // 128-col tiles
    const int nb    = ncols * (Mt >> 7);
    const int bid   = blockIdx.x;

    if (bid >= nb) {   // tail work, overlapped with the GEMM blocks
        if (tail == 1) {
            exscan_dev(tp0, tp1, tp2, (int*)As);
        } else if (tail == 2) {
            int e = (bid - nb) * 256 + tid;
            if (e < EPLUS) {
                int srcN, dstN;
                if (e < EDGES) { srcN = tp0[e]; dstN = tp0[EDGES + e]; }
                else           { srcN = dstN = e - EDGES; }
                int pos = atomicAdd(&tp1[dstN], 1);
                tp2[pos] = srcN;
            }
        }
        return;
    }

    const int bt   = bid % ncols;
    const int row0 = (bid / ncols) * 128;
    const int col0 = bt * 128;
    const int wave = tid >> 6;
    const int lane = tid & 63;
    const int wy = wave >> 1, wx = wave & 1;

    const int lrow = lane >> 2;
    const int lk   = (lane & 3) * 8;

    f32x4 acc[4][4] = {};

    for (int k0 = 0; k0 < K; k0 += 32) {
        if (k0) __syncthreads();
        #pragma unroll
        for (int r = 0; r < 2; ++r) {
            const int chunk = r * 4 + wave;
            const int trow  = chunk * 16 + lrow;
            GLD_LDS16(A16 + (size_t)(row0 + trow) * K + k0 + lk,
                      &As[chunk * 512]);
            GLD_LDS16(Bt16 + (size_t)(col0 + trow) * K + k0 + lk,
                      &Bs[chunk * 512]);
        }
        __syncthreads();

        const int quad = lane >> 4;
        const int l16  = lane & 15;
        f16x8 af[4], bf[4];
        #pragma unroll
        for (int m = 0; m < 4; ++m)
            af[m] = *(const f16x8*)&As[(wy * 64 + m * 16 + l16) * 32 + quad * 8];
        #pragma unroll
        for (int n = 0; n < 4; ++n)
            bf[n] = *(const f16x8*)&Bs[(wx * 64 + n * 16 + l16) * 32 + quad * 8];
        #pragma unroll
        for (int m = 0; m < 4; ++m)
            #pragma unroll
            for (int n = 0; n < 4; ++n)
                acc[m][n] = __builtin_amdgcn_mfma_f32_16x16x32_f16(
                    af[m], bf[n], acc[m][n], 0, 0, 0);
    }

    const int quad = lane >> 4;
    const int l16  = lane & 15;
    #pragma unroll
    for (int m = 0; m < 4; ++m) {
        #pragma unroll
        for (int n = 0; n < 4; ++n) {
            const int col = col0 + wx * 64 + n * 16 + l16;
            const float bv = bias ? bias[col] : 0.0f;
            #pragma unroll
            for (int r = 0; r < 4; ++r) {
                const int row = row0 + wy * 64 + m * 16 + quad * 4 + r;
                C16[(size_t)row * Nn + col] = (_Float16)(acc[m][n][r] + bv);
            }
        }
    }

    if (ssrc) {   // fused per-head scores: wave's 64 cols == one head
        const int head = bt * 2 + wx;
        float a_sv[4], a_dv[4];
        #pragma unroll
        for (int n = 0; n < 4; ++n) {
            const int col = col0 + wx * 64 + n * 16 + l16;
            a_sv[n] = a_s[col & 511];
            a_dv[n] = a_d[col & 511];
        }
        #pragma unroll
        for (int m = 0; m < 4; ++m) {
            #pragma unroll
            for (int r = 0; r < 4; ++r) {
                float vs = acc[m][0][r] * a_sv[0] + acc[m][1][r] * a_sv[1]
                         + acc[m][2][r] * a_sv[2] + acc[m][3][r] * a_sv[3];
                float vd = acc[m][0][r] * a_dv[0] + acc[m][1][r] * a_dv[1]
                         + acc[m][2][r] * a_dv[2] + acc[m][3][r] * a_dv[3];
                vs += __shfl_xor(vs, 1); vs += __shfl_xor(vs, 2);
                vs += __shfl_xor(vs, 4); vs += __shfl_xor(vs, 8);
                vd += __shfl_xor(vd, 1); vd += __shfl_xor(vd, 2);
                vd += __shfl_xor(vd, 4); vd += __shfl_xor(vd, 8);
                if (l16 == 0) {
                    const int row = row0 + wy * 64 + m * 16 + quad * 4 + r;
                    ssrc[(size_t)row * HEADS8 + head] = vs;
                    sdst[(size_t)row * HEADS8 + head] = vd;
                }
            }
        }
    }
}

// ---------------------------------------------------------------------------
// fp16 MFMA GEMM, N=64 (layer 3) with fused NH=1 scores. Padded rows.
// ---------------------------------------------------------------------------
__global__ __launch_bounds__(256) void gemm_f16_mfma_n64(
    const _Float16* __restrict__ A16, const _Float16* __restrict__ Bt16,
    _Float16* __restrict__ C16,
    float* __restrict__ ssrc, float* __restrict__ sdst,
    const float* __restrict__ a_s, const float* __restrict__ a_d)
{
    __shared__ _Float16 As[64 * 32] __attribute__((aligned(16)));
    __shared__ _Float16 Bs[64 * 32] __attribute__((aligned(16)));
    __shared__ float sS[2][64];
    __shared__ float sD[2][64];
    const int tid  = threadIdx.x;
    const int wave = tid >> 6;
    const int lane = tid & 63;
    const int row0 = blockIdx.x * 64;
    const int wy = wave >> 1, wx = wave & 1;

    const int lrow = lane >> 2;
    const int lk   = (lane & 3) * 8;

    f32x4 acc[2][2] = {};

    for (int k0 = 0; k0 < 512; k0 += 32) {
        if (k0) __syncthreads();
        {
            const int trow = wave * 16 + lrow;
            GLD_LDS16(A16 + (size_t)(row0 + trow) * 512 + k0 + lk, &As[wave * 512]);
            GLD_LDS16(Bt16 + (size_t)trow * 512 + k0 + lk, &Bs[wave * 512]);
        }
        __syncthreads();

        const int quad = lane >> 4;
        const int l16  = lane & 15;
        f16x8 af[2], bf[2];
        #pragma unroll
        for (int m = 0; m < 2; ++m)
            af[m] = *(const f16x8*)&As[(wy * 32 + m * 16 + l16) * 32 + quad * 8];
        #pragma unroll
        for (int n = 0; n < 2; ++n)
            bf[n] = *(const f16x8*)&Bs[(wx * 32 + n * 16 + l16) * 32 + quad * 8];
        #pragma unroll
        for (int m = 0; m < 2; ++m)
            #pragma unroll
            for (int n = 0; n < 2; ++n)
                acc[m][n] = __builtin_amdgcn_mfma_f32_16x16x32_f16(
                    af[m], bf[n], acc[m][n], 0, 0, 0);
    }

    const int quad = lane >> 4;
    const int l16  = lane & 15;
    #pragma unroll
    for (int m = 0; m < 2; ++m)
        #pragma unroll
        for (int n = 0; n < 2; ++n) {
            const int col = wx * 32 + n * 16 + l16;
            #pragma unroll
            for (int r = 0; r < 4; ++r) {
                const int row = row0 + wy * 32 + m * 16 + quad * 4 + r;
                C16[(size_t)row * 64 + col] = (_Float16)acc[m][n][r];
            }
        }

    // fused scores (heads=1)
    {
        float a_sv[2], a_dv[2];
        #pragma unroll
        for (int n = 0; n < 2; ++n) {
            const int col = wx * 32 + n * 16 + l16;
            a_sv[n] = a_s[col];
            a_dv[n] = a_d[col];
        }
        #pragma unroll
        for (int m = 0; m < 2; ++m)
            #pragma unroll
            for (int r = 0; r < 4; ++r) {
                float vs = acc[m][0][r] * a_sv[0] + acc[m][1][r] * a_sv[1];
                float vd = acc[m][0][r] * a_dv[0] + acc[m][1][r] * a_dv[1];
                vs += __shfl_xor(vs, 1); vs += __shfl_xor(vs, 2);
                vs += __shfl_xor(vs, 4); vs += __shfl_xor(vs, 8);
                vd += __shfl_xor(vd, 1); vd += __shfl_xor(vd, 2);
                vd += __shfl_xor(vd, 4); vd += __shfl_xor(vd, 8);
                if (l16 == 0) {
                    const int lr = wy * 32 + m * 16 + quad * 4 + r;
                    sS[wx][lr] = vs;
                    sD[wx][lr] = vd;
                }
            }
        __syncthreads();
        if (wx == 0 && l16 == 0) {
            #pragma unroll
            for (int m = 0; m < 2; ++m)
                #pragma unroll
                for (int r = 0; r < 4; ++r) {
                    const int lr = wy * 32 + m * 16 + quad * 4 + r;
                    const int row = row0 + lr;
                    ssrc[row] = sS[0][lr] + sS[1][lr];
                    sdst[row] = sD[0][lr] + sD[1][lr];
                }
        }
    }
}

// ---------------------------------------------------------------------------
// Segment-softmax aggregation, NH=8 fp16, single pass; f16 output.
// 1 node per 64-thread block; gather loop unrolled x8 (8 loads in flight).
// ---------------------------------------------------------------------------
__global__ __launch_bounds__(64) void gat_aggregate8(
    const _Float16* __restrict__ Hf, const float* __restrict__ ssrc,
    const float* __restrict__ sdst, const int* __restrict__ off,
    const int* __restrict__ csr, const float* __restrict__ bias,
    _Float16* __restrict__ out)
{
    const int n    = blockIdx.x;
    const int lane = threadIdx.x;
    const int head = lane >> 3;
    const int e0 = off[n], e1 = off[n + 1];

    float4 sd0 = ((const float4*)(sdst + n * 8))[0];
    float4 sd1 = ((const float4*)(sdst + n * 8))[1];
    float sd[8] = {sd0.x, sd0.y, sd0.z, sd0.w, sd1.x, sd1.y, sd1.z, sd1.w};

    __shared__ float exL[64 * 8];
    __shared__ int   srcL[64];
    float acc[8]  = {};
    float ssum[8] = {};
    for (int base = e0; base < e1; base += 64) {
        int cnt = e1 - base; if (cnt > 64) cnt = 64;
        if (lane < cnt) {
            int s = csr[base + lane];
            srcL[lane] = s;
            float4 s0 = ((const float4*)(ssrc + s * 8))[0];
            float4 s1 = ((const float4*)(ssrc + s * 8))[1];
            float lv[8] = {s0.x, s0.y, s0.z, s0.w, s1.x, s1.y, s1.z, s1.w};
            #pragma unroll
            for (int h = 0; h < 8; ++h) {
                float l = lv[h] + sd[h];
                l = (l > 0.f) ? l : 0.2f * l;
                float ex = __expf(l);
                exL[lane * 8 + h] = ex;
                ssum[h] += ex;
            }
        }
        __syncthreads();
        int j = 0;
        for (; j + 8 <= cnt; j += 8) {
            f16x8 hv[8];
            #pragma unroll
            for (int u = 0; u < 8; ++u)
                hv[u] = *(const f16x8*)(Hf + (size_t)srcL[j + u] * HC + lane * 8);
            #pragma unroll
            for (int u = 0; u < 8; ++u) {
                const float a = exL[(j + u) * 8 + head];
                #pragma unroll
                for (int c = 0; c < 8; ++c)
                    acc[c] = fmaf(a, (float)hv[u][c], acc[c]);
            }
        }
        for (; j + 4 <= cnt; j += 4) {
            const int s0 = srcL[j],     s1 = srcL[j + 1];
            const int s2 = srcL[j + 2], s3 = srcL[j + 3];
            f16x8 h0 = *(const f16x8*)(Hf + (size_t)s0 * HC + lane * 8);
            f16x8 h1 = *(const f16x8*)(Hf + (size_t)s1 * HC + lane * 8);
            f16x8 h2 = *(const f16x8*)(Hf + (size_t)s2 * HC + lane * 8);
            f16x8 h3 = *(const f16x8*)(Hf + (size_t)s3 * HC + lane * 8);
            const float a0 = exL[(j)     * 8 + head];
            const float a1 = exL[(j + 1) * 8 + head];
            const float a2 = exL[(j + 2) * 8 + head];
            const float a3 = exL[(j + 3) * 8 + head];
            #pragma unroll
            for (int c = 0; c < 8; ++c) {
                acc[c] = fmaf(a0, (float)h0[c], acc[c]);
                acc[c] = fmaf(a1, (float)h1[c], acc[c]);
                acc[c] = fmaf(a2, (float)h2[c], acc[c]);
                acc[c] = fmaf(a3, (float)h3[c], acc[c]);
            }
        }
        for (; j < cnt; ++j) {
            const int s = srcL[j];
            f16x8 hv = *(const f16x8*)(Hf + (size_t)s * HC + lane * 8);
            const float al = exL[j * 8 + head];
            #pragma unroll
            for (int c = 0; c < 8; ++c)
                acc[c] = fmaf(al, (float)hv[c], acc[c]);
        }
        __syncthreads();
    }
    #pragma unroll
    for (int h = 0; h < 8; ++h)
        #pragma unroll
        for (int o = 1; o < 64; o <<= 1)
            ssum[h] += __shfl_xor(ssum[h], o);

    const float inv = 1.0f / (ssum[head] + 1e-16f);
    const float* bp = bias + lane * 8;
    f16x8 ov;
    #pragma unroll
    for (int c = 0; c < 8; ++c)
        ov[c] = (_Float16)(acc[c] * inv + bp[c]);
    *(f16x8*)(out + (size_t)n * HC + lane * 8) = ov;
}

// NH=1 fp16 aggregate (layer 3), single pass, lane = channel; unrolled x4
__global__ __launch_bounds__(64) void gat_aggregate1(
    const _Float16* __restrict__ Hf, const float* __restrict__ ssrc,
    const float* __restrict__ sdst, const int* __restrict__ off,
    const int* __restrict__ csr, const float* __restrict__ bias,
    float* __restrict__ out)
{
    const int n    = blockIdx.x;
    const int lane = threadIdx.x;
    const int e0 = off[n], e1 = off[n + 1];
    const float sd = sdst[n];

    __shared__ float exL[64];
    __shared__ int   srcL[64];
    float acc = 0.f, ssum = 0.f;
    for (int base = e0; base < e1; base += 64) {
        int cnt = e1 - base; if (cnt > 64) cnt = 64;
        if (lane < cnt) {
            int s = csr[base + lane];
            srcL[lane] = s;
            float l = ssrc[s] + sd;
            l = (l > 0.f) ? l : 0.2f * l;
            float ex = __expf(l);
            exL[lane] = ex;
            ssum += ex;
        }
        __syncthreads();
        int j = 0;
        for (; j + 4 <= cnt; j += 4) {
            const int s0 = srcL[j],     s1 = srcL[j + 1];
            const int s2 = srcL[j + 2], s3 = srcL[j + 3];
            float h0 = (float)Hf[(size_t)s0 * 64 + lane];
            float h1 = (float)Hf[(size_t)s1 * 64 + lane];
            float h2 = (float)Hf[(size_t)s2 * 64 + lane];
            float h3 = (float)Hf[(size_t)s3 * 64 + lane];
            acc = fmaf(exL[j],     h0, acc);
            acc = fmaf(exL[j + 1], h1, acc);
            acc = fmaf(exL[j + 2], h2, acc);
            acc = fmaf(exL[j + 3], h3, acc);
        }
        for (; j < cnt; ++j)
            acc = fmaf(exL[j], (float)Hf[(size_t)srcL[j] * 64 + lane], acc);
        __syncthreads();
    }
    #pragma unroll
    for (int o = 1; o < 64; o <<= 1)
        ssum += __shfl_xor(ssum, o);

    out[(size_t)n * 64 + lane] = acc / (ssum + 1e-16f) + bias[lane];
}

// ---------------------------------------------------------------------------
// BatchNorm stats (f16): partials ONLY (no fence/ticket/finalize).
// ---------------------------------------------------------------------------
__global__ __launch_bounds__(256) void bn_stats_f16(
    const _Float16* __restrict__ x,
    float* __restrict__ psum, float* __restrict__ psq)   // [NSTAT][HC] each
{
    const int t    = threadIdx.x;
    const int lane = t & 63;
    const int wv   = t >> 6;
    const int w    = blockIdx.x * 4 + wv;     // wave id 0..1023
    float s[8] = {}, q[8] = {};
    #pragma unroll
    for (int k = 0; k < RPAD / 2048; ++k) {   // 5 iterations, 2 rows each
        const int r0 = w + k * 2048;
        f16x8 v0 = *(const f16x8*)(x + (size_t)r0 * HC + lane * 8);
        f16x8 v1 = *(const f16x8*)(x + (size_t)(r0 + 1024) * HC + lane * 8);
        #pragma unroll
        for (int j = 0; j < 8; ++j) {
            float f0 = (float)v0[j], f1 = (float)v1[j];
            s[j] += f0 + f1;
            q[j] += f0 * f0 + f1 * f1;
        }
    }
    __shared__ float ls[4][HC];
    __shared__ float lq[4][HC];
    #pragma unroll
    for (int j = 0; j < 8; ++j) {
        ls[wv][lane * 8 + j] = s[j];
        lq[wv][lane * 8 + j] = q[j];
    }
    __syncthreads();
    const size_t bo = (size_t)blockIdx.x * HC;
    #pragma unroll
    for (int k = 0; k < 2; ++k) {
        const int ch = t + k * 256;
        psum[bo + ch] = ls[0][ch] + ls[1][ch] + ls[2][ch] + ls[3][ch];
        psq [bo + ch] = lq[0][ch] + lq[1][ch] + lq[2][ch] + lq[3][ch];
    }
}

// fp32 stats (layer 3, cols=64): same structure, 64 blocks, RPAD rows
__global__ __launch_bounds__(256) void bn_stats3(
    const float* __restrict__ x,
    float* __restrict__ psum, float* __restrict__ psq)   // [NSTAT3][CH] each
{
    const int t    = threadIdx.x;
    const int c4   = (t & 15) * 4;  // 4 cols; 16 threads cover a 256B row
    const int rsub = t >> 4;        // 0..15: 16 rows in flight per block
    float s[4] = {}, q[4] = {};
    #pragma unroll
    for (int k = 0; k < RPAD / 1024; ++k) {   // 10 iterations
        const int r = blockIdx.x * 16 + rsub + k * 1024;
        float4 v = *(const float4*)(x + (size_t)r * CH + c4);
        s[0] += v.x; q[0] += v.x * v.x;
        s[1] += v.y; q[1] += v.y * v.y;
        s[2] += v.z; q[2] += v.z * v.z;
        s[3] += v.w; q[3] += v.w * v.w;
    }
    __shared__ float ls[16][CH];
    __shared__ float lq[16][CH];
    #pragma unroll
    for (int j = 0; j < 4; ++j) {
        ls[rsub][c4 + j] = s[j];
        lq[rsub][c4 + j] = q[j];
    }
    __syncthreads();
    if (t < CH) {
        float tot = 0.f;
        #pragma unroll
        for (int p = 0; p < 16; ++p) tot += ls[p][t];
        psum[(size_t)blockIdx.x * CH + t] = tot;
    } else if (t < 2 * CH) {
        const int ch = t - CH;
        float tot = 0.f;
        #pragma unroll
        for (int p = 0; p < 16; ++p) tot += lq[p][ch];
        psq[(size_t)blockIdx.x * CH + ch] = tot;
    }
}

// ---------------------------------------------------------------------------
// Generic BN finalize: grid = cols/16 blocks; 16 threads cooperate per
// channel (strided partial reads, LDS reduce). Kernel boundary is the sync.
// ---------------------------------------------------------------------------
__global__ __launch_bounds__(256) void bn_finalize(
    const float* __restrict__ psum, const float* __restrict__ psq,
    const float* __restrict__ g, const float* __restrict__ be,
    float* __restrict__ scale, float* __restrict__ shift,
    float invN, int cols, int np)
{
    const int t  = threadIdx.x;
    const int pg = t >> 4;            // 0..15 partial-group
    const int cl = t & 15;
    const int ch = blockIdx.x * 16 + cl;
    float S = 0.f, Q = 0.f;
    for (int p = pg; p < np; p += 16) {
        S += psum[(size_t)p * cols + ch];
        Q += psq [(size_t)p * cols + ch];
    }
    __shared__ float lsS[16][16];
    __shared__ float lsQ[16][16];
    lsS[pg][cl] = S;
    lsQ[pg][cl] = Q;
    __syncthreads();
    if (t < 16) {
        float S2 = 0.f, Q2 = 0.f;
        #pragma unroll
        for (int p = 0; p < 16; ++p) { S2 += lsS[p][t]; Q2 += lsQ[p][t]; }
        const int c = blockIdx.x * 16 + t;
        float mu  = S2 * invN;
        float var = Q2 * invN - mu * mu;
        float sc  = g[c] / sqrtf(var + 1e-5f);
        scale[c] = sc;
        shift[c] = be[c] - mu * sc;
    }
}

// f16 in, f16 residual, f16 out: v = elu(x*scale + shift) + res  (16B/lane)
__global__ void bn_apply16(const _Float16* __restrict__ xin,
                           const _Float16* __restrict__ res,
                           const float* __restrict__ scale,
                           const float* __restrict__ shift,
                           _Float16* __restrict__ out, size_t total8)
{
    size_t i = (size_t)blockIdx.x * blockDim.x + threadIdx.x;
    if (i >= total8) return;
    int c = (int)((i * 8) & (size_t)(HC - 1));
    f16x8 xv = ((const f16x8*)xin)[i];
    f16x8 rv = ((const f16x8*)res)[i];
    float4 sa = *(const float4*)(scale + c);
    float4 sb = *(const float4*)(scale + c + 4);
    float4 ha = *(const float4*)(shift + c);
    float4 hb = *(const float4*)(shift + c + 4);
    float sc[8] = {sa.x, sa.y, sa.z, sa.w, sb.x, sb.y, sb.z, sb.w};
    float sh[8] = {ha.x, ha.y, ha.z, ha.w, hb.x, hb.y, hb.z, hb.w};
    f16x8 o;
    #pragma unroll
    for (int j = 0; j < 8; ++j) {
        float v = (float)xv[j] * sc[j] + sh[j];
        v = (v > 0.f) ? v : expm1f(v);
        o[j] = (_Float16)(v + (float)rv[j]);
    }
    ((f16x8*)out)[i] = o;
}

// ---------------------------------------------------------------------------
// Fused global-mean-pool + BN3 affine (affine commutes with mean) + linear
// ---------------------------------------------------------------------------
__global__ __launch_bounds__(256) void pool_linear(
    const float* __restrict__ x, const int* __restrict__ goff,
    const float* __restrict__ W, const float* __restrict__ b,
    const float* __restrict__ scale, const float* __restrict__ shift,
    float* __restrict__ out)
{
    const int g    = blockIdx.x;
    const int lane = threadIdx.x & 63;   // channel
    const int wave = threadIdx.x >> 6;   // 0..3
    const int r0 = goff[g], r1 = goff[g + 1];
    float s = 0.f;
    for (int r = r0 + wave; r < r1; r += 4)
        s += x[(size_t)r * CH + lane];
    __shared__ float red[4][CH];
    __shared__ float mean_l[CH];
    red[wave][lane] = s;
    __syncthreads();
    if (wave == 0) {
        float tot = red[0][lane] + red[1][lane] + red[2][lane] + red[3][lane];
        float cnt = (float)(r1 - r0);
        float m = tot / fmaxf(cnt, 1.0f);
        mean_l[lane] = m * scale[lane] + shift[lane];   // BN3 applied on mean
    }
    __syncthreads();
    if (threadIdx.x < NCLS) {
        const int j = threadIdx.x;
        float acc = b[j];
        for (int c = 0; c < CH; ++c)
            acc = fmaf(mean_l[c], W[c * NCLS + j], acc);
        out[g * NCLS + j] = acc;
    }
}

// ---------------------------------------------------------------------------
// Host launcher
// ---------------------------------------------------------------------------
extern "C" void kernel_launch(void* const* d_in, const int* in_sizes, int n_in,
                              void* d_out, int out_size, void* d_ws, size_t ws_size,
                              hipStream_t stream)
{
    const float* x_in  = (const float*)d_in[0];
    const int*   ei    = (const int*)  d_in[1];
    const int*   batch = (const int*)  d_in[2];
    const float* enc_W = (const float*)d_in[3];
    const float* enc_b = (const float*)d_in[4];
    const float* W1  = (const float*)d_in[5];
    const float* as1 = (const float*)d_in[6];
    const float* ad1 = (const float*)d_in[7];
    const float* b1  = (const float*)d_in[8];
    const float* g1  = (const float*)d_in[9];
    const float* be1 = (const float*)d_in[10];
    const float* W2  = (const float*)d_in[11];
    const float* as2 = (const float*)d_in[12];
    const float* ad2 = (const float*)d_in[13];
    const float* b2  = (const float*)d_in[14];
    const float* g2  = (const float*)d_in[15];
    const float* be2 = (const float*)d_in[16];
    const float* W3  = (const float*)d_in[17];
    const float* as3 = (const float*)d_in[18];
    const float* ad3 = (const float*)d_in[19];
    const float* b3  = (const float*)d_in[20];
    const float* g3  = (const float*)d_in[21];
    const float* be3 = (const float*)d_in[22];
    const float* linW = (const float*)d_in[23];
    const float* linb = (const float*)d_in[24];
    float* out = (float*)d_out;

    char* ws = (char*)d_ws;
    size_t off_b = 0;
    auto alloc = [&](size_t bytes) -> void* {
        void* p = ws + off_b;
        off_b = (off_b + bytes + 255) & ~(size_t)255;
        return p;
    };
    _Float16* f16A   = (_Float16*)alloc((size_t)MPAD * HC * 2);   // act buf A
    _Float16* f16B   = (_Float16*)alloc((size_t)MPAD * HC * 2);   // act buf B
    _Float16* H16    = (_Float16*)alloc((size_t)MPAD * HC * 2);   // GAT features
    _Float16* g16    = (_Float16*)alloc((size_t)RPAD * HC * 2);   // aggregate out (padded)
    _Float16* h3_16  = (_Float16*)alloc((size_t)MPAD * CH * 2);
    float*    g3o    = (float*)alloc((size_t)RPAD * CH * 4);      // padded
    _Float16* encWt  = (_Float16*)alloc((size_t)HC * FIN * 2);
    _Float16* W1t    = (_Float16*)alloc((size_t)HC * HC * 2);
    _Float16* W2t    = (_Float16*)alloc((size_t)HC * HC * 2);
    _Float16* W3t    = (_Float16*)alloc((size_t)CH * HC * 2);
    float* ssrc   = (float*)alloc((size_t)MPAD * HEADS8 * 4);
    float* sdst   = (float*)alloc((size_t)MPAD * HEADS8 * 4);
    int*   deg    = (int*)  alloc((size_t)NNODES * 4);
    int*   offp   = (int*)  alloc((size_t)(NNODES + 1) * 4);
    int*   cursor = (int*)  alloc((size_t)NNODES * 4);
    int*   csr    = (int*)  alloc((size_t)EPLUS * 4);
    int*   goff   = (int*)  alloc((size_t)(NG + 1) * 4);
    float* psum   = (float*)alloc((size_t)NSTAT * HC * 4);   // 512 KB
    float* psq    = (float*)alloc((size_t)NSTAT * HC * 4);
    float* psum3  = (float*)alloc((size_t)NSTAT3 * CH * 4);  // 16 KB
    float* psq3   = (float*)alloc((size_t)NSTAT3 * CH * 4);
    float* bnsc   = (float*)alloc(HC * 4);
    float* bnsh   = (float*)alloc(HC * 4);

    // ---- Prep: histogram+goff+pad-zeroing, x fp16 convert, weight transposes
    hipMemsetAsync(deg, 0, (size_t)NNODES * 4, stream);
    prep_all<<<PREP_CNT + PREP_CONV + 1024, 256, 0, stream>>>(
        ei, deg, batch, goff, x_in, f16A, enc_W, W1, W2, W3,
        encWt, W1t, W2t, W3t,
        g16 + (size_t)NNODES * HC, g3o + (size_t)NNODES * CH);

    const int NB = (HC / 128) * (MPAD / 128);        // 316 GEMM blocks
    const int SCAT = (EPLUS + 255) / 256;            // 665 scatter blocks

    // ---- Encoder GEMM; tail block runs the degree exclusive-scan
    gemm_f16_mfma<<<NB + 1, 256, 0, stream>>>(
        f16A, encWt, enc_b, f16B, nullptr, nullptr, nullptr, nullptr,
        MPAD, HC, FIN, 1, deg, offp, cursor);

    const size_t total8 = (size_t)NNODES * HC / 8;
    const int apply_blocks = (int)((total8 + 255) / 256);
    const float invN = 1.0f / NNODES;

    // ---- Layer 1: GEMM (+fused scores) with CSR scatter in tail blocks
    gemm_f16_mfma<<<NB + SCAT, 256, 0, stream>>>(
        f16B, W1t, nullptr, H16, ssrc, sdst, as1, ad1,
        MPAD, HC, HC, 2, ei, cursor, csr);
    gat_aggregate8<<<NNODES, 64, 0, stream>>>(H16, ssrc, sdst, offp, csr,
                                              b1, g16);
    bn_stats_f16<<<NSTAT, 256, 0, stream>>>(g16, psum, psq);
    bn_finalize<<<HC / 16, 256, 0, stream>>>(psum, psq, g1, be1, bnsc, bnsh,
                                             invN, HC, NSTAT);
    bn_apply16<<<apply_blocks, 256, 0, stream>>>(g16, f16B, bnsc, bnsh,
                                                 f16A, total8);

    // ---- Layer 2
    gemm_f16_mfma<<<NB, 256, 0, stream>>>(
        f16A, W2t, nullptr, H16, ssrc, sdst, as2, ad2,
        MPAD, HC, HC, 0, nullptr, nullptr, nullptr);
    gat_aggregate8<<<NNODES, 64, 0, stream>>>(H16, ssrc, sdst, offp, csr,
                                              b2, g16);
    bn_stats_f16<<<NSTAT, 256, 0, stream>>>(g16, psum, psq);
    bn_finalize<<<HC / 16, 256, 0, stream>>>(psum, psq, g2, be2, bnsc, bnsh,
                                             invN, HC, NSTAT);
    bn_apply16<<<apply_blocks, 256, 0, stream>>>(g16, f16A, bnsc, bnsh,
                                                 f16B, total8);

    // ---- Layer 3 (heads=1, C=64)
    gemm_f16_mfma_n64<<<MPAD / 64, 256, 0, stream>>>(f16B, W3t, h3_16,
                                                     ssrc, sdst, as3, ad3);
    gat_aggregate1<<<NNODES, 64, 0, stream>>>(h3_16, ssrc, sdst, offp, csr,
                                              b3, g3o);
    bn_stats3<<<NSTAT3, 256, 0, stream>>>(g3o, psum3, psq3);
    bn_finalize<<<CH / 16, 256, 0, stream>>>(psum3, psq3, g3, be3, bnsc, bnsh,
                                             invN, CH, NSTAT3);

    // ---- Fused pool + BN3 affine + final linear
    pool_linear<<<NG, 256, 0, stream>>>(g3o, goff, linW, linb, bnsc, bnsh,
                                        out);
}